// Round 4
// baseline (3506.136 us; speedup 1.0000x reference)
//
#include <hip/hip_runtime.h>
#include <hip/hip_bf16.h>

using bf16 = __hip_bfloat16;
typedef __bf16 bf16x8 __attribute__((ext_vector_type(8)));
typedef float f32x4 __attribute__((ext_vector_type(4)));

// Sizes (fixed): B=8 S=32 N=64 F_NODE=32 TRI=2016 DIN=2048 H=4 DOUT=256 R=1024
// OUT=2016, G=B*S=256 graphs

__device__ __forceinline__ void unp2(unsigned int u, float& a, float& b) {
  a = __uint_as_float(u << 16);
  b = __uint_as_float(u & 0xffff0000u);
}

__device__ __forceinline__ bf16x8 cvt8(float4 a, float4 b) {
  bf16x8 r;
  r[0] = (__bf16)a.x; r[1] = (__bf16)a.y; r[2] = (__bf16)a.z; r[3] = (__bf16)a.w;
  r[4] = (__bf16)b.x; r[5] = (__bf16)b.y; r[6] = (__bf16)b.z; r[7] = (__bf16)b.w;
  return r;
}

// ---------------------------------------------------------------------------
// Grid barrier (sense reversal).  State memset to 0 before each persistent
// launch.  Device-scope atomics + threadfence for cross-XCD visibility.
// ---------------------------------------------------------------------------
__device__ __forceinline__ void grid_barrier(unsigned* cnt, unsigned* sns,
                                             unsigned nblk, unsigned* lsense) {
  __threadfence();
  __syncthreads();
  if (threadIdx.x == 0) {
    unsigned my = *lsense ^ 1u; *lsense = my;
    unsigned old = __hip_atomic_fetch_add(cnt, 1u, __ATOMIC_ACQ_REL,
                                          __HIP_MEMORY_SCOPE_AGENT);
    if (old == nblk - 1u) {
      __hip_atomic_store(cnt, 0u, __ATOMIC_RELAXED, __HIP_MEMORY_SCOPE_AGENT);
      __hip_atomic_store(sns, my, __ATOMIC_RELEASE, __HIP_MEMORY_SCOPE_AGENT);
    } else {
      while (__hip_atomic_load(sns, __ATOMIC_ACQUIRE,
                               __HIP_MEMORY_SCOPE_AGENT) != my)
        __builtin_amdgcn_s_sleep(2);
    }
  }
  __syncthreads();
  __threadfence();
}

// ---------------------------------------------------------------------------
// Persistent GRU layer scan.  256 blocks x 256 threads, 1 launch per layer.
// Block owns 4 hidden units j; W_hh slice (48 KB) LDS-resident for all steps.
// ---------------------------------------------------------------------------
__global__ __launch_bounds__(256, 1) void gru_persist_k(
    const float* __restrict__ X,    // [256, 3072] gi
    const float* __restrict__ Whh,  // [3072, 1024]
    const float* __restrict__ bhh,  // [3072]
    float* __restrict__ y,          // [256, 1024]
    unsigned* __restrict__ bar) {
  __shared__ float ws[12][1024];    // [gate*4 + j_l][k]
  const int tid = threadIdx.x;
  const int w = tid >> 6, lane = tid & 63;
  const int b = lane >> 3, kg = lane & 7;
  const int j0 = blockIdx.x * 4, j = j0 + w;
  unsigned lsense = 0;
#pragma unroll
  for (int q = 0; q < 12; ++q) {
    int idx = q * 256 + tid;
    int row = idx >> 8, k = (idx & 255) * 4;
    int gr = (row >> 2) * 1024 + j0 + (row & 3);
    *(float4*)&ws[row][k] = *(const float4*)&Whh[(size_t)gr * 1024 + k];
  }
  const float br = bhh[j], bz = bhh[1024 + j], bn_ = bhh[2048 + j];
  __syncthreads();
  for (int s = 0; s < 32; ++s) {
    float4 hv[32];
    if (s == 0) {
#pragma unroll
      for (int m = 0; m < 32; ++m) hv[m] = make_float4(0.f, 0.f, 0.f, 0.f);
    } else {
      const float* hb_ = y + (size_t)(b * 32 + s - 1) * 1024;
#pragma unroll
      for (int m = 0; m < 32; ++m) hv[m] = *(const float4*)&hb_[4 * (kg + 8 * m)];
    }
    float g0 = 0.f, g1 = 0.f, g2 = 0.f;
#pragma unroll
    for (int m = 0; m < 32; ++m) {
      const int kf = 4 * (kg + 8 * m);
      float4 h4 = hv[m];
      float4 w0 = *(const float4*)&ws[w][kf];
      float4 w1 = *(const float4*)&ws[4 + w][kf];
      float4 w2 = *(const float4*)&ws[8 + w][kf];
      g0 += h4.x * w0.x + h4.y * w0.y + h4.z * w0.z + h4.w * w0.w;
      g1 += h4.x * w1.x + h4.y * w1.y + h4.z * w1.z + h4.w * w1.w;
      g2 += h4.x * w2.x + h4.y * w2.y + h4.z * w2.z + h4.w * w2.w;
    }
#pragma unroll
    for (int d = 1; d < 8; d <<= 1) {
      g0 += __shfl_xor(g0, d); g1 += __shfl_xor(g1, d); g2 += __shfl_xor(g2, d);
    }
    if (kg == 0) {
      const float* gip = X + (size_t)(b * 32 + s) * 3072;
      float ir = gip[j], iz = gip[1024 + j], inn = gip[2048 + j];
      float r = 1.0f / (1.0f + __expf(-(ir + g0 + br)));
      float z = 1.0f / (1.0f + __expf(-(iz + g1 + bz)));
      float hp = (s == 0) ? 0.f : y[(size_t)(b * 32 + s - 1) * 1024 + j];
      float n = tanhf(inn + r * (g2 + bn_));
      y[(size_t)(b * 32 + s) * 1024 + j] = (1.0f - z) * n + z * hp;
    }
    if (s < 31) grid_barrier(bar, bar + 1, gridDim.x, &lsense);
  }
}

// ---------------------------------------------------------------------------
// X0 GEMM: Cp[z][m][n] = sum_{k in chunk z} A[m,k]*B[n,k]
// A: [256, K] bf16 (full 32 bf16/row staged: 4x uint4).  B: [N, K] fp32.
// M-tile = 256 (full M), N-tile 128, BK=32, register prefetch.
// ---------------------------------------------------------------------------
__global__ __launch_bounds__(256) void gemm_bt16_k(const __bf16* __restrict__ A,
                                                   const float* __restrict__ Bm,
                                                   float* __restrict__ Cp,
                                                   int N, int K, int ksper) {
  __shared__ __bf16 As[256][40];   // 80B row stride: aligned, ~2-way bank alias
  __shared__ __bf16 Bs[128][40];
  const int tid = threadIdx.x;
  const int bn = blockIdx.x * 128;
  const int lane = tid & 63, wv = tid >> 6;
  const int wr = wv >> 1, wc = wv & 1;
  const int lr = lane & 15, kh = lane >> 4;
  const int brow = tid >> 1, bhalf = tid & 1;
  f32x4 acc[8][4] = {};
  const int kstot = K >> 5;
  int ks0 = blockIdx.z * ksper;
  int ks1 = ks0 + ksper; if (ks1 > kstot) ks1 = kstot;
  uint4 ra0, ra1, ra2, ra3; float4 rb0, rb1, rb2, rb3;
  {
    const int k0 = ks0 << 5;
    const uint4* ap = (const uint4*)(A + (size_t)tid * K + k0);
    ra0 = ap[0]; ra1 = ap[1]; ra2 = ap[2]; ra3 = ap[3];
    const float* bp = Bm + (size_t)(bn + brow) * K + k0 + bhalf * 16;
    rb0 = ((const float4*)bp)[0]; rb1 = ((const float4*)bp)[1];
    rb2 = ((const float4*)bp)[2]; rb3 = ((const float4*)bp)[3];
  }
  for (int ks = ks0; ks < ks1; ++ks) {
    __syncthreads();
    *(uint4*)&As[tid][0]  = ra0;
    *(uint4*)&As[tid][8]  = ra1;
    *(uint4*)&As[tid][16] = ra2;
    *(uint4*)&As[tid][24] = ra3;
    *(bf16x8*)&Bs[brow][bhalf * 16] = cvt8(rb0, rb1);
    *(bf16x8*)&Bs[brow][bhalf * 16 + 8] = cvt8(rb2, rb3);
    __syncthreads();
    if (ks + 1 < ks1) {  // prefetch next K-tile into regs; overlaps with MFMA
      const int k0 = (ks + 1) << 5;
      const uint4* ap = (const uint4*)(A + (size_t)tid * K + k0);
      ra0 = ap[0]; ra1 = ap[1]; ra2 = ap[2]; ra3 = ap[3];
      const float* bp = Bm + (size_t)(bn + brow) * K + k0 + bhalf * 16;
      rb0 = ((const float4*)bp)[0]; rb1 = ((const float4*)bp)[1];
      rb2 = ((const float4*)bp)[2]; rb3 = ((const float4*)bp)[3];
    }
    bf16x8 bfv[4];
#pragma unroll
    for (int ni = 0; ni < 4; ++ni)
      bfv[ni] = *(const bf16x8*)&Bs[wc * 64 + ni * 16 + lr][kh * 8];
#pragma unroll
    for (int mi = 0; mi < 8; ++mi) {
      bf16x8 af = *(const bf16x8*)&As[wr * 128 + mi * 16 + lr][kh * 8];
#pragma unroll
      for (int ni = 0; ni < 4; ++ni)
        acc[mi][ni] = __builtin_amdgcn_mfma_f32_16x16x32_bf16(af, bfv[ni],
                                                              acc[mi][ni], 0, 0, 0);
    }
  }
  float* cp = Cp + (size_t)blockIdx.z * 256 * N;
#pragma unroll
  for (int mi = 0; mi < 8; ++mi) {
#pragma unroll
    for (int ni = 0; ni < 4; ++ni) {
      const int row = wr * 128 + mi * 16 + kh * 4;
      const int col = bn + wc * 64 + ni * 16 + lr;
#pragma unroll
      for (int j = 0; j < 4; ++j)
        cp[(size_t)(row + j) * N + col] = acc[mi][ni][j];
    }
  }
}

// ---------------------------------------------------------------------------
// fp32-input MFMA GEMM (he: B [K,N]; X1: B [N,K]) with split-K.
// ---------------------------------------------------------------------------
template <bool BT>
__global__ __launch_bounds__(256) void mfma_gemm_k(const float* __restrict__ A,
                                                   const float* __restrict__ Bm,
                                                   float* __restrict__ Cp,
                                                   int M, int N, int K,
                                                   int lda, int ldb, int ksper) {
  __shared__ __bf16 As[128][40];
  __shared__ __bf16 Bs[128][40];
  const int tid = threadIdx.x;
  const int bm = blockIdx.y * 128, bn = blockIdx.x * 128;
  const int lane = tid & 63, wv = tid >> 6;
  const int wr = wv >> 1, wc = wv & 1;
  const int lr = lane & 15, kh = lane >> 4;
  f32x4 acc[4][4] = {};
  const int kstot = K >> 5;
  int ks0 = blockIdx.z * ksper;
  int ks1 = ks0 + ksper; if (ks1 > kstot) ks1 = kstot;
  for (int ks = ks0; ks < ks1; ++ks) {
    const int k0 = ks << 5;
    __syncthreads();
    {
      const int row = tid >> 1, half = tid & 1;
      const float* ap = A + (size_t)(bm + row) * lda + k0 + half * 16;
      float4 f0 = ((const float4*)ap)[0], f1 = ((const float4*)ap)[1];
      float4 f2 = ((const float4*)ap)[2], f3 = ((const float4*)ap)[3];
      *(bf16x8*)&As[row][half * 16] = cvt8(f0, f1);
      *(bf16x8*)&As[row][half * 16 + 8] = cvt8(f2, f3);
    }
    if (BT) {
      const int row = tid >> 1, half = tid & 1;
      const float* bp = Bm + (size_t)(bn + row) * ldb + k0 + half * 16;
      float4 f0 = ((const float4*)bp)[0], f1 = ((const float4*)bp)[1];
      float4 f2 = ((const float4*)bp)[2], f3 = ((const float4*)bp)[3];
      *(bf16x8*)&Bs[row][half * 16] = cvt8(f0, f1);
      *(bf16x8*)&Bs[row][half * 16 + 8] = cvt8(f2, f3);
    } else {
      const int kk = tid >> 3, ng = tid & 7;
      const float* bp = Bm + (size_t)(k0 + kk) * ldb + bn + ng * 16;
      float4 f[4];
#pragma unroll
      for (int q = 0; q < 4; ++q) f[q] = ((const float4*)bp)[q];
#pragma unroll
      for (int q = 0; q < 4; ++q) {
        Bs[ng * 16 + q * 4 + 0][kk] = (__bf16)f[q].x;
        Bs[ng * 16 + q * 4 + 1][kk] = (__bf16)f[q].y;
        Bs[ng * 16 + q * 4 + 2][kk] = (__bf16)f[q].z;
        Bs[ng * 16 + q * 4 + 3][kk] = (__bf16)f[q].w;
      }
    }
    __syncthreads();
    bf16x8 af[4], bfv[4];
#pragma unroll
    for (int mi = 0; mi < 4; ++mi)
      af[mi] = *(const bf16x8*)&As[wr * 64 + mi * 16 + lr][kh * 8];
#pragma unroll
    for (int ni = 0; ni < 4; ++ni)
      bfv[ni] = *(const bf16x8*)&Bs[wc * 64 + ni * 16 + lr][kh * 8];
#pragma unroll
    for (int mi = 0; mi < 4; ++mi)
#pragma unroll
      for (int ni = 0; ni < 4; ++ni)
        acc[mi][ni] = __builtin_amdgcn_mfma_f32_16x16x32_bf16(af[mi], bfv[ni],
                                                              acc[mi][ni], 0, 0, 0);
  }
  float* cp = Cp + (size_t)blockIdx.z * M * N;
#pragma unroll
  for (int mi = 0; mi < 4; ++mi) {
#pragma unroll
    for (int ni = 0; ni < 4; ++ni) {
      const int row = bm + wr * 64 + mi * 16 + kh * 4;
      const int col = bn + wc * 64 + ni * 16 + lr;
#pragma unroll
      for (int j = 0; j < 4; ++j)
        cp[(size_t)(row + j) * N + col] = acc[mi][ni][j];
    }
  }
}

// C[i] = bias[i%N] + sum_sk Cp[sk][i]
__global__ __launch_bounds__(256) void reduce_k(const float* __restrict__ Cp,
                                                const float* __restrict__ bias,
                                                float* __restrict__ C,
                                                int MN, int N, int nsk) {
  int i = (blockIdx.x * 256 + threadIdx.x) * 4;
  if (i >= MN) return;
  float4 s = make_float4(0.f, 0.f, 0.f, 0.f);
  if (bias) s = *(const float4*)&bias[i % N];
  for (int sk = 0; sk < nsk; ++sk) {
    float4 p = *(const float4*)&Cp[(size_t)sk * MN + i];
    s.x += p.x; s.y += p.y; s.z += p.z; s.w += p.w;
  }
  *(float4*)&C[i] = s;
}

// ---------------------------------------------------------------------------
// h[g,n,c] = he[g,c] + sum_f x_node[g,n,f] * Wg[f,c]   -> stored bf16
// ---------------------------------------------------------------------------
__global__ __launch_bounds__(256) void node_h_k(const float* __restrict__ xn,
                                                const float* __restrict__ Wg,
                                                const float* __restrict__ he,
                                                bf16* __restrict__ hbuf) {
  __shared__ float xns[64][32];
  __shared__ float wgs[32][256];
  const int cq = blockIdx.x, g = blockIdx.y;
  const int tid = threadIdx.x;
  for (int idx = tid; idx < 2048; idx += 256) xns[idx >> 5][idx & 31] = xn[g * 2048 + idx];
  for (int r = 0; r < 32; ++r) wgs[r][tid] = Wg[r * 1024 + cq * 256 + tid];
  __syncthreads();
  const float hev = he[g * 1024 + cq * 256 + tid];
  for (int n0 = 0; n0 < 64; n0 += 8) {
    float acc[8];
#pragma unroll
    for (int nn = 0; nn < 8; ++nn) acc[nn] = hev;
    for (int f = 0; f < 32; ++f) {
      float w = wgs[f][tid];
#pragma unroll
      for (int nn = 0; nn < 8; ++nn) acc[nn] += xns[n0 + nn][f] * w;
    }
#pragma unroll
    for (int nn = 0; nn < 8; ++nn)
      hbuf[(size_t)(g * 64 + n0 + nn) * 1024 + cq * 256 + tid] = __float2bfloat16(acc[nn]);
  }
}

// ---------------------------------------------------------------------------
// a_s[row,hd] = sum_e h[row, hd*256+e] * att_src[hd,e]; same for a_d.
// ---------------------------------------------------------------------------
__global__ __launch_bounds__(256) void as_ad_k(const bf16* __restrict__ hbuf,
                                               const float* __restrict__ att_s,
                                               const float* __restrict__ att_d,
                                               float* __restrict__ as_o,
                                               float* __restrict__ ad_o) {
  const int tid = threadIdx.x;
  const int lane = tid & 63, wv = tid >> 6;
  const int row = blockIdx.x * 4 + wv;
  const int hd = lane >> 4;
  const int e0 = (lane & 15) * 16;
  float as_r[16], ad_r[16];
#pragma unroll
  for (int q = 0; q < 4; ++q) {
    float4 v = *(const float4*)(att_s + hd * 256 + e0 + q * 4);
    as_r[q * 4 + 0] = v.x; as_r[q * 4 + 1] = v.y; as_r[q * 4 + 2] = v.z; as_r[q * 4 + 3] = v.w;
    float4 w = *(const float4*)(att_d + hd * 256 + e0 + q * 4);
    ad_r[q * 4 + 0] = w.x; ad_r[q * 4 + 1] = w.y; ad_r[q * 4 + 2] = w.z; ad_r[q * 4 + 3] = w.w;
  }
  const uint4* hp = (const uint4*)(hbuf + (size_t)row * 1024 + lane * 16);
  uint4 p0 = hp[0], p1 = hp[1];
  float hv[16];
  unp2(p0.x, hv[0], hv[1]);  unp2(p0.y, hv[2], hv[3]);
  unp2(p0.z, hv[4], hv[5]);  unp2(p0.w, hv[6], hv[7]);
  unp2(p1.x, hv[8], hv[9]);  unp2(p1.y, hv[10], hv[11]);
  unp2(p1.z, hv[12], hv[13]); unp2(p1.w, hv[14], hv[15]);
  float ps = 0.f, pd = 0.f;
#pragma unroll
  for (int i = 0; i < 16; ++i) { ps += as_r[i] * hv[i]; pd += ad_r[i] * hv[i]; }
#pragma unroll
  for (int m = 1; m < 16; m <<= 1) { ps += __shfl_xor(ps, m); pd += __shfl_xor(pd, m); }
  if ((lane & 15) == 0) { as_o[row * 4 + hd] = ps; ad_o[row * 4 + hd] = pd; }
}

// ---------------------------------------------------------------------------
// Per graph g: softmax over sources + head-mean aggregation + bias + relu.
// Writes seq as bf16 (same rounding point the GEMM applied before).
// ---------------------------------------------------------------------------
__global__ __launch_bounds__(256) void attn_agg_k(const bf16* __restrict__ hbuf,
                                                  const float* __restrict__ as_i,
                                                  const float* __restrict__ ad_i,
                                                  const float* __restrict__ bgat,
                                                  __bf16* __restrict__ seq) {
  __shared__ float ass[256], ads[256], bgs[256];
  __shared__ float alpha[4][64][64];   // [hd][j][i]
  __shared__ float hq[64][260];        // one head-quarter of h, fp32
  const int g = blockIdx.x, tid = threadIdx.x;
  ass[tid] = as_i[g * 256 + tid];
  ads[tid] = ad_i[g * 256 + tid];
  bgs[tid] = bgat[tid];
  __syncthreads();
  {
    const int hd = tid >> 6, i = tid & 63;
    const float ad = ads[i * 4 + hd];
    float m = -1e30f;
    for (int j = 0; j < 64; ++j) {
      float s = ad + ass[j * 4 + hd];
      s = s > 0.0f ? s : 0.2f * s;
      m = fmaxf(m, s);
    }
    float sum = 0.0f;
    for (int j = 0; j < 64; ++j) {
      float s = ad + ass[j * 4 + hd];
      s = s > 0.0f ? s : 0.2f * s;
      sum += __expf(s - m);
    }
    const float inv = 1.0f / sum;
    for (int j = 0; j < 64; ++j) {
      float s = ad + ass[j * 4 + hd];
      s = s > 0.0f ? s : 0.2f * s;
      alpha[hd][j][i] = __expf(s - m) * inv;
    }
  }
  const int i = tid & 63, eq = tid >> 6;
  float acc[64] = {};
  for (int hd = 0; hd < 4; ++hd) {
    __syncthreads();
    for (int idx = tid; idx < 2048; idx += 256) {
      int j = idx >> 5, ch = idx & 31;
      uint4 p = *(const uint4*)(hbuf + (size_t)(g * 64 + j) * 1024 + hd * 256 + ch * 8);
      float f0, f1, f2, f3, f4, f5, f6, f7;
      unp2(p.x, f0, f1); unp2(p.y, f2, f3); unp2(p.z, f4, f5); unp2(p.w, f6, f7);
      *(float4*)&hq[j][ch * 8] = make_float4(f0, f1, f2, f3);
      *(float4*)&hq[j][ch * 8 + 4] = make_float4(f4, f5, f6, f7);
    }
    __syncthreads();
    for (int j = 0; j < 64; ++j) {
      const float a = alpha[hd][j][i];
      const float* hr = &hq[j][eq * 64];
#pragma unroll
      for (int q = 0; q < 16; ++q) {
        float4 hv = *(const float4*)(hr + q * 4);
        acc[q * 4 + 0] += a * hv.x; acc[q * 4 + 1] += a * hv.y;
        acc[q * 4 + 2] += a * hv.z; acc[q * 4 + 3] += a * hv.w;
      }
    }
  }
  __bf16* op = seq + (size_t)g * 16384 + i * 256 + eq * 64;
#pragma unroll
  for (int q = 0; q < 8; ++q) {
    float4 lo, hi;
    lo.x = fmaxf(bgs[eq * 64 + q * 8 + 0] + 0.25f * acc[q * 8 + 0], 0.0f);
    lo.y = fmaxf(bgs[eq * 64 + q * 8 + 1] + 0.25f * acc[q * 8 + 1], 0.0f);
    lo.z = fmaxf(bgs[eq * 64 + q * 8 + 2] + 0.25f * acc[q * 8 + 2], 0.0f);
    lo.w = fmaxf(bgs[eq * 64 + q * 8 + 3] + 0.25f * acc[q * 8 + 3], 0.0f);
    hi.x = fmaxf(bgs[eq * 64 + q * 8 + 4] + 0.25f * acc[q * 8 + 4], 0.0f);
    hi.y = fmaxf(bgs[eq * 64 + q * 8 + 5] + 0.25f * acc[q * 8 + 5], 0.0f);
    hi.z = fmaxf(bgs[eq * 64 + q * 8 + 6] + 0.25f * acc[q * 8 + 6], 0.0f);
    hi.w = fmaxf(bgs[eq * 64 + q * 8 + 7] + 0.25f * acc[q * 8 + 7], 0.0f);
    *(bf16x8*)(op + q * 8) = cvt8(lo, hi);
  }
}

// ---------------------------------------------------------------------------
// out[b,o] = b_fc[o] + sum_k y1[b,31,k] * Wfc[k,o]
// ---------------------------------------------------------------------------
__global__ __launch_bounds__(256) void fc_k(const float* __restrict__ y1,
                                            const float* __restrict__ Wfc,
                                            const float* __restrict__ bfc,
                                            float* __restrict__ out) {
  __shared__ float As[8][1024];
  const int tid = threadIdx.x;
  for (int idx = tid; idx < 8192; idx += 256) {
    int b = idx >> 10, k = idx & 1023;
    As[b][k] = y1[(size_t)(b * 32 + 31) * 1024 + k];
  }
  __syncthreads();
  const int ol = tid >> 2, kq = tid & 3;
  const int o = blockIdx.x * 64 + ol;
  float acc[8] = {};
  if (o < 2016) {
    for (int i2 = 0; i2 < 256; ++i2) {
      int k = i2 * 4 + kq;
      float w = Wfc[(size_t)k * 2016 + o];
#pragma unroll
      for (int b = 0; b < 8; ++b) acc[b] += As[b][k] * w;
    }
  }
#pragma unroll
  for (int b = 0; b < 8; ++b) {
    acc[b] += __shfl_xor(acc[b], 1);
    acc[b] += __shfl_xor(acc[b], 2);
  }
  if (kq == 0 && o < 2016) {
#pragma unroll
    for (int b = 0; b < 8; ++b) out[b * 2016 + o] = acc[b] + bfc[o];
  }
}

// ---------------------------------------------------------------------------
extern "C" void kernel_launch(void* const* d_in, const int* in_sizes, int n_in,
                              void* d_out, int out_size, void* d_ws, size_t ws_size,
                              hipStream_t stream) {
  (void)in_sizes; (void)n_in; (void)out_size; (void)ws_size;
  const float* x_node = (const float*)d_in[0];
  const float* x_edge = (const float*)d_in[1];
  // d_in[2] = edge_index: complete graph + self loops -> dense; unused.
  const float* W_gat = (const float*)d_in[3];
  const float* att_s = (const float*)d_in[4];
  const float* att_d = (const float*)d_in[5];
  const float* b_gat = (const float*)d_in[6];
  const float* W_ih0 = (const float*)d_in[7];
  const float* W_hh0 = (const float*)d_in[8];
  const float* b_ih0 = (const float*)d_in[9];
  const float* b_hh0 = (const float*)d_in[10];
  const float* W_ih1 = (const float*)d_in[11];
  const float* W_hh1 = (const float*)d_in[12];
  const float* b_ih1 = (const float*)d_in[13];
  const float* b_hh1 = (const float*)d_in[14];
  const float* W_fc  = (const float*)d_in[15];
  const float* b_fc  = (const float*)d_in[16];

  char* ws = (char*)d_ws;
  size_t off = 0;
  float*  he  = (float*)(ws + off);  off += 256u * 1024 * 4;           // 1 MB
  float*  a_s = (float*)(ws + off);  off += 256u * 64 * 4 * 4;         // 256 KB
  float*  a_d = (float*)(ws + off);  off += 256u * 64 * 4 * 4;         // 256 KB
  bf16*   hb  = (bf16*)(ws + off);   off += 256u * 64 * 1024 * 2;      // 32 MB
  __bf16* seq = (__bf16*)(ws + off); off += 256u * 16384 * 2;          // 8 MB
  float*  X0  = (float*)(ws + off);  off += 256u * 3072 * 4;           // 3 MB
  float*  y0  = (float*)(ws + off);  off += 256u * 1024 * 4;           // 1 MB
  float*  X1  = (float*)(ws + off);  off += 256u * 3072 * 4;           // 3 MB
  float*  y1  = (float*)(ws + off);  off += 256u * 1024 * 4;           // 1 MB
  off = (off + 255) & ~(size_t)255;
  unsigned* bar = (unsigned*)(ws + off); off += 256;                   // barrier
  float*  Cp  = (float*)(ws + off);  off += (size_t)16 * 256 * 3072 * 4; // 48 MB

  // 1) he = x_edge @ W_gat[32:, :]   (M=256, N=1024, K=2016, B is [K,N]) SK=8
  mfma_gemm_k<false><<<dim3(8, 2, 8), 256, 0, stream>>>(
      x_edge, W_gat + 32 * 1024, Cp, 256, 1024, 2016, 2016, 1024, 8);
  reduce_k<<<256, 256, 0, stream>>>(Cp, nullptr, he, 256 * 1024, 1024, 8);
  // 2) h = node-proj + he (bf16)
  node_h_k<<<dim3(4, 256), 256, 0, stream>>>(x_node, W_gat, he, hb);
  // 3) attention logits
  as_ad_k<<<4096, 256, 0, stream>>>(hb, att_s, att_d, a_s, a_d);
  // 4) softmax + aggregation + relu -> seq [256, 16384] bf16
  attn_agg_k<<<256, 256, 0, stream>>>(hb, a_s, a_d, b_gat, seq);
  // 5) X0 = seq @ W_ih0^T + b_ih0   (M=256 full-tile, N=3072, K=16384) SK=16
  gemm_bt16_k<<<dim3(24, 1, 16), 256, 0, stream>>>(seq, W_ih0, Cp,
                                                   3072, 16384, 32);
  reduce_k<<<768, 256, 0, stream>>>(Cp, b_ih0, X0, 256 * 3072, 3072, 16);
  // 6) GRU layer 0: persistent scan (grid barrier between steps)
  hipMemsetAsync(bar, 0, 8, stream);
  gru_persist_k<<<256, 256, 0, stream>>>(X0, W_hh0, b_hh0, y0, bar);
  // 7) X1 = y0 @ W_ih1^T + b_ih1    (M=256, N=3072, K=1024) SK=4
  mfma_gemm_k<true><<<dim3(24, 2, 4), 256, 0, stream>>>(
      y0, W_ih1, Cp, 256, 3072, 1024, 1024, 1024, 8);
  reduce_k<<<768, 256, 0, stream>>>(Cp, b_ih1, X1, 256 * 3072, 3072, 4);
  // 8) GRU layer 1: persistent scan
  hipMemsetAsync(bar, 0, 8, stream);
  gru_persist_k<<<256, 256, 0, stream>>>(X1, W_hh1, b_hh1, y1, bar);
  // 9) out = y1[:, 31] @ W_fc + b_fc
  fc_k<<<32, 256, 0, stream>>>(y1, W_fc, b_fc, (float*)d_out);
}

// Round 5
// 1292.861 us; speedup vs baseline: 2.7119x; 2.7119x over previous
//
#include <hip/hip_runtime.h>
#include <hip/hip_bf16.h>

using bf16 = __hip_bfloat16;
typedef __bf16 bf16x8 __attribute__((ext_vector_type(8)));
typedef float f32x4 __attribute__((ext_vector_type(4)));

// Sizes (fixed): B=8 S=32 N=64 F_NODE=32 TRI=2016 DIN=2048 H=4 DOUT=256 R=1024
// OUT=2016, G=B*S=256 graphs

__device__ __forceinline__ void unp2(unsigned int u, float& a, float& b) {
  a = __uint_as_float(u << 16);
  b = __uint_as_float(u & 0xffff0000u);
}

__device__ __forceinline__ bf16x8 cvt8(float4 a, float4 b) {
  bf16x8 r;
  r[0] = (__bf16)a.x; r[1] = (__bf16)a.y; r[2] = (__bf16)a.z; r[3] = (__bf16)a.w;
  r[4] = (__bf16)b.x; r[5] = (__bf16)b.y; r[6] = (__bf16)b.z; r[7] = (__bf16)b.w;
  return r;
}

// ---------------------------------------------------------------------------
// Grid barrier, cache-op-frugal version.
// - __syncthreads() drains each wave's vmcnt -> all block stores are in L2.
// - ONE thread per block does: release fence (L2 writeback), relaxed arrive,
//   relaxed-poll (no per-poll invalidate!), acquire fence (invalidate).
// - bounded spin re-fences as a liveness hedge.
// ---------------------------------------------------------------------------
__device__ __forceinline__ void grid_barrier(unsigned* cnt, unsigned* sns,
                                             unsigned nblk, unsigned* lsense) {
  __syncthreads();
  if (threadIdx.x == 0) {
    unsigned my = *lsense ^ 1u; *lsense = my;
    __threadfence();  // release: flush this XCD's L2 to coherence point
    unsigned old = __hip_atomic_fetch_add(cnt, 1u, __ATOMIC_RELAXED,
                                          __HIP_MEMORY_SCOPE_AGENT);
    if (old == nblk - 1u) {
      __hip_atomic_store(cnt, 0u, __ATOMIC_RELAXED, __HIP_MEMORY_SCOPE_AGENT);
      __hip_atomic_store(sns, my, __ATOMIC_RELEASE, __HIP_MEMORY_SCOPE_AGENT);
    } else {
      int spins = 0;
      while (__hip_atomic_load(sns, __ATOMIC_RELAXED,
                               __HIP_MEMORY_SCOPE_AGENT) != my) {
        __builtin_amdgcn_s_sleep(4);
        if (++spins >= 8192) { __threadfence(); spins = 0; }
      }
    }
    __threadfence();  // acquire: invalidate L1/L2 so step-s reads are fresh
  }
  __syncthreads();
}

// ---------------------------------------------------------------------------
// Persistent GRU layer scan.  128 blocks x 256 threads, 1 launch per layer.
// Block owns 8 hidden units j (j0=bid*8); wave w handles jA=j0+w, jB=j0+4+w.
// W_hh slice (24 x 1024 fp32 = 96 KB) LDS-resident for all 32 steps.
// Lane (b=lane>>3, kg=lane&7) covers k = 4*(kg+8m); ws reads broadcast
// across the 8 b-groups (same address -> free).
// ---------------------------------------------------------------------------
__global__ __launch_bounds__(256, 1) void gru_persist_k(
    const float* __restrict__ X,    // [256, 3072] gi
    const float* __restrict__ Whh,  // [3072, 1024]
    const float* __restrict__ bhh,  // [3072]
    float* __restrict__ y,          // [256, 1024]
    unsigned* __restrict__ bar) {
  __shared__ float ws[24][1024];    // [gate*8 + j_l][k]
  const int tid = threadIdx.x;
  const int w = tid >> 6, lane = tid & 63;
  const int b = lane >> 3, kg = lane & 7;
  const int j0 = blockIdx.x * 8;
  const int jA = j0 + w, jB = j0 + 4 + w;
  unsigned lsense = 0;
#pragma unroll
  for (int q = 0; q < 24; ++q) {               // 6144 float4, 24/thread
    int idx = q * 256 + tid;
    int row = idx >> 8, k4 = (idx & 255) * 4;  // row = gate*8 + j_l
    int gr = (row >> 3) * 1024 + j0 + (row & 7);
    *(float4*)&ws[row][k4] = *(const float4*)&Whh[(size_t)gr * 1024 + k4];
  }
  const float brA = bhh[jA], bzA = bhh[1024 + jA], bnA = bhh[2048 + jA];
  const float brB = bhh[jB], bzB = bhh[1024 + jB], bnB = bhh[2048 + jB];
  __syncthreads();
  for (int s = 0; s < 32; ++s) {
    float4 hv[32];
    if (s == 0) {
#pragma unroll
      for (int m = 0; m < 32; ++m) hv[m] = make_float4(0.f, 0.f, 0.f, 0.f);
    } else {
      const float* hb_ = y + (size_t)(b * 32 + s - 1) * 1024;
#pragma unroll
      for (int m = 0; m < 32; ++m) hv[m] = *(const float4*)&hb_[4 * (kg + 8 * m)];
    }
    float g0a = 0.f, g1a = 0.f, g2a = 0.f;
    float g0b = 0.f, g1b = 0.f, g2b = 0.f;
#pragma unroll
    for (int m = 0; m < 32; ++m) {
      const int kf = 4 * (kg + 8 * m);
      float4 h4 = hv[m];
      float4 wr_ = *(const float4*)&ws[w][kf];
      float4 wz_ = *(const float4*)&ws[8 + w][kf];
      float4 wn_ = *(const float4*)&ws[16 + w][kf];
      g0a += h4.x * wr_.x + h4.y * wr_.y + h4.z * wr_.z + h4.w * wr_.w;
      g1a += h4.x * wz_.x + h4.y * wz_.y + h4.z * wz_.z + h4.w * wz_.w;
      g2a += h4.x * wn_.x + h4.y * wn_.y + h4.z * wn_.z + h4.w * wn_.w;
      float4 vr_ = *(const float4*)&ws[4 + w][kf];
      float4 vz_ = *(const float4*)&ws[12 + w][kf];
      float4 vn_ = *(const float4*)&ws[20 + w][kf];
      g0b += h4.x * vr_.x + h4.y * vr_.y + h4.z * vr_.z + h4.w * vr_.w;
      g1b += h4.x * vz_.x + h4.y * vz_.y + h4.z * vz_.z + h4.w * vz_.w;
      g2b += h4.x * vn_.x + h4.y * vn_.y + h4.z * vn_.z + h4.w * vn_.w;
    }
#pragma unroll
    for (int d = 1; d < 8; d <<= 1) {
      g0a += __shfl_xor(g0a, d); g1a += __shfl_xor(g1a, d); g2a += __shfl_xor(g2a, d);
      g0b += __shfl_xor(g0b, d); g1b += __shfl_xor(g1b, d); g2b += __shfl_xor(g2b, d);
    }
    if (kg == 0) {
      const float* gip = X + (size_t)(b * 32 + s) * 3072;
      const float* hrow = y + (size_t)(b * 32 + s - 1) * 1024;
      float* yrow = y + (size_t)(b * 32 + s) * 1024;
      {
        float r = 1.0f / (1.0f + __expf(-(gip[jA] + g0a + brA)));
        float z = 1.0f / (1.0f + __expf(-(gip[1024 + jA] + g1a + bzA)));
        float n = tanhf(gip[2048 + jA] + r * (g2a + bnA));
        float hp = (s == 0) ? 0.f : hrow[jA];
        yrow[jA] = (1.0f - z) * n + z * hp;
      }
      {
        float r = 1.0f / (1.0f + __expf(-(gip[jB] + g0b + brB)));
        float z = 1.0f / (1.0f + __expf(-(gip[1024 + jB] + g1b + bzB)));
        float n = tanhf(gip[2048 + jB] + r * (g2b + bnB));
        float hp = (s == 0) ? 0.f : hrow[jB];
        yrow[jB] = (1.0f - z) * n + z * hp;
      }
    }
    if (s < 31) grid_barrier(bar, bar + 1, gridDim.x, &lsense);
  }
}

// ---------------------------------------------------------------------------
// X0 GEMM: Cp[z][m][n] = sum_{k in chunk z} A[m,k]*B[n,k]
// A: [256, K] bf16 (full 32 bf16/row staged).  B: [N, K] fp32.
// M-tile = 256 (full M), N-tile 128, BK=32, register prefetch.
// ---------------------------------------------------------------------------
__global__ __launch_bounds__(256) void gemm_bt16_k(const __bf16* __restrict__ A,
                                                   const float* __restrict__ Bm,
                                                   float* __restrict__ Cp,
                                                   int N, int K, int ksper) {
  __shared__ __bf16 As[256][40];   // 80B row stride: aligned, ~2-way bank alias
  __shared__ __bf16 Bs[128][40];
  const int tid = threadIdx.x;
  const int bn = blockIdx.x * 128;
  const int lane = tid & 63, wv = tid >> 6;
  const int wr = wv >> 1, wc = wv & 1;
  const int lr = lane & 15, kh = lane >> 4;
  const int brow = tid >> 1, bhalf = tid & 1;
  f32x4 acc[8][4] = {};
  const int kstot = K >> 5;
  int ks0 = blockIdx.z * ksper;
  int ks1 = ks0 + ksper; if (ks1 > kstot) ks1 = kstot;
  uint4 ra0, ra1, ra2, ra3; float4 rb0, rb1, rb2, rb3;
  {
    const int k0 = ks0 << 5;
    const uint4* ap = (const uint4*)(A + (size_t)tid * K + k0);
    ra0 = ap[0]; ra1 = ap[1]; ra2 = ap[2]; ra3 = ap[3];
    const float* bp = Bm + (size_t)(bn + brow) * K + k0 + bhalf * 16;
    rb0 = ((const float4*)bp)[0]; rb1 = ((const float4*)bp)[1];
    rb2 = ((const float4*)bp)[2]; rb3 = ((const float4*)bp)[3];
  }
  for (int ks = ks0; ks < ks1; ++ks) {
    __syncthreads();
    *(uint4*)&As[tid][0]  = ra0;
    *(uint4*)&As[tid][8]  = ra1;
    *(uint4*)&As[tid][16] = ra2;
    *(uint4*)&As[tid][24] = ra3;
    *(bf16x8*)&Bs[brow][bhalf * 16] = cvt8(rb0, rb1);
    *(bf16x8*)&Bs[brow][bhalf * 16 + 8] = cvt8(rb2, rb3);
    __syncthreads();
    if (ks + 1 < ks1) {  // prefetch next K-tile into regs; overlaps with MFMA
      const int k0 = (ks + 1) << 5;
      const uint4* ap = (const uint4*)(A + (size_t)tid * K + k0);
      ra0 = ap[0]; ra1 = ap[1]; ra2 = ap[2]; ra3 = ap[3];
      const float* bp = Bm + (size_t)(bn + brow) * K + k0 + bhalf * 16;
      rb0 = ((const float4*)bp)[0]; rb1 = ((const float4*)bp)[1];
      rb2 = ((const float4*)bp)[2]; rb3 = ((const float4*)bp)[3];
    }
    bf16x8 bfv[4];
#pragma unroll
    for (int ni = 0; ni < 4; ++ni)
      bfv[ni] = *(const bf16x8*)&Bs[wc * 64 + ni * 16 + lr][kh * 8];
#pragma unroll
    for (int mi = 0; mi < 8; ++mi) {
      bf16x8 af = *(const bf16x8*)&As[wr * 128 + mi * 16 + lr][kh * 8];
#pragma unroll
      for (int ni = 0; ni < 4; ++ni)
        acc[mi][ni] = __builtin_amdgcn_mfma_f32_16x16x32_bf16(af, bfv[ni],
                                                              acc[mi][ni], 0, 0, 0);
    }
  }
  float* cp = Cp + (size_t)blockIdx.z * 256 * N;
#pragma unroll
  for (int mi = 0; mi < 8; ++mi) {
#pragma unroll
    for (int ni = 0; ni < 4; ++ni) {
      const int row = wr * 128 + mi * 16 + kh * 4;
      const int col = bn + wc * 64 + ni * 16 + lr;
#pragma unroll
      for (int j = 0; j < 4; ++j)
        cp[(size_t)(row + j) * N + col] = acc[mi][ni][j];
    }
  }
}

// ---------------------------------------------------------------------------
// fp32-input MFMA GEMM (he: B [K,N]; X1: B [N,K]) with split-K.
// ---------------------------------------------------------------------------
template <bool BT>
__global__ __launch_bounds__(256) void mfma_gemm_k(const float* __restrict__ A,
                                                   const float* __restrict__ Bm,
                                                   float* __restrict__ Cp,
                                                   int M, int N, int K,
                                                   int lda, int ldb, int ksper) {
  __shared__ __bf16 As[128][40];
  __shared__ __bf16 Bs[128][40];
  const int tid = threadIdx.x;
  const int bm = blockIdx.y * 128, bn = blockIdx.x * 128;
  const int lane = tid & 63, wv = tid >> 6;
  const int wr = wv >> 1, wc = wv & 1;
  const int lr = lane & 15, kh = lane >> 4;
  f32x4 acc[4][4] = {};
  const int kstot = K >> 5;
  int ks0 = blockIdx.z * ksper;
  int ks1 = ks0 + ksper; if (ks1 > kstot) ks1 = kstot;
  for (int ks = ks0; ks < ks1; ++ks) {
    const int k0 = ks << 5;
    __syncthreads();
    {
      const int row = tid >> 1, half = tid & 1;
      const float* ap = A + (size_t)(bm + row) * lda + k0 + half * 16;
      float4 f0 = ((const float4*)ap)[0], f1 = ((const float4*)ap)[1];
      float4 f2 = ((const float4*)ap)[2], f3 = ((const float4*)ap)[3];
      *(bf16x8*)&As[row][half * 16] = cvt8(f0, f1);
      *(bf16x8*)&As[row][half * 16 + 8] = cvt8(f2, f3);
    }
    if (BT) {
      const int row = tid >> 1, half = tid & 1;
      const float* bp = Bm + (size_t)(bn + row) * ldb + k0 + half * 16;
      float4 f0 = ((const float4*)bp)[0], f1 = ((const float4*)bp)[1];
      float4 f2 = ((const float4*)bp)[2], f3 = ((const float4*)bp)[3];
      *(bf16x8*)&Bs[row][half * 16] = cvt8(f0, f1);
      *(bf16x8*)&Bs[row][half * 16 + 8] = cvt8(f2, f3);
    } else {
      const int kk = tid >> 3, ng = tid & 7;
      const float* bp = Bm + (size_t)(k0 + kk) * ldb + bn + ng * 16;
      float4 f[4];
#pragma unroll
      for (int q = 0; q < 4; ++q) f[q] = ((const float4*)bp)[q];
#pragma unroll
      for (int q = 0; q < 4; ++q) {
        Bs[ng * 16 + q * 4 + 0][kk] = (__bf16)f[q].x;
        Bs[ng * 16 + q * 4 + 1][kk] = (__bf16)f[q].y;
        Bs[ng * 16 + q * 4 + 2][kk] = (__bf16)f[q].z;
        Bs[ng * 16 + q * 4 + 3][kk] = (__bf16)f[q].w;
      }
    }
    __syncthreads();
    bf16x8 af[4], bfv[4];
#pragma unroll
    for (int mi = 0; mi < 4; ++mi)
      af[mi] = *(const bf16x8*)&As[wr * 64 + mi * 16 + lr][kh * 8];
#pragma unroll
    for (int ni = 0; ni < 4; ++ni)
      bfv[ni] = *(const bf16x8*)&Bs[wc * 64 + ni * 16 + lr][kh * 8];
#pragma unroll
    for (int mi = 0; mi < 4; ++mi)
#pragma unroll
      for (int ni = 0; ni < 4; ++ni)
        acc[mi][ni] = __builtin_amdgcn_mfma_f32_16x16x32_bf16(af[mi], bfv[ni],
                                                              acc[mi][ni], 0, 0, 0);
  }
  float* cp = Cp + (size_t)blockIdx.z * M * N;
#pragma unroll
  for (int mi = 0; mi < 4; ++mi) {
#pragma unroll
    for (int ni = 0; ni < 4; ++ni) {
      const int row = bm + wr * 64 + mi * 16 + kh * 4;
      const int col = bn + wc * 64 + ni * 16 + lr;
#pragma unroll
      for (int j = 0; j < 4; ++j)
        cp[(size_t)(row + j) * N + col] = acc[mi][ni][j];
    }
  }
}

// C[i] = bias[i%N] + sum_sk Cp[sk][i]
__global__ __launch_bounds__(256) void reduce_k(const float* __restrict__ Cp,
                                                const float* __restrict__ bias,
                                                float* __restrict__ C,
                                                int MN, int N, int nsk) {
  int i = (blockIdx.x * 256 + threadIdx.x) * 4;
  if (i >= MN) return;
  float4 s = make_float4(0.f, 0.f, 0.f, 0.f);
  if (bias) s = *(const float4*)&bias[i % N];
  for (int sk = 0; sk < nsk; ++sk) {
    float4 p = *(const float4*)&Cp[(size_t)sk * MN + i];
    s.x += p.x; s.y += p.y; s.z += p.z; s.w += p.w;
  }
  *(float4*)&C[i] = s;
}

// ---------------------------------------------------------------------------
// h[g,n,c] = he[g,c] + sum_f x_node[g,n,f] * Wg[f,c]   -> stored bf16
// ---------------------------------------------------------------------------
__global__ __launch_bounds__(256) void node_h_k(const float* __restrict__ xn,
                                                const float* __restrict__ Wg,
                                                const float* __restrict__ he,
                                                bf16* __restrict__ hbuf) {
  __shared__ float xns[64][32];
  __shared__ float wgs[32][256];
  const int cq = blockIdx.x, g = blockIdx.y;
  const int tid = threadIdx.x;
  for (int idx = tid; idx < 2048; idx += 256) xns[idx >> 5][idx & 31] = xn[g * 2048 + idx];
  for (int r = 0; r < 32; ++r) wgs[r][tid] = Wg[r * 1024 + cq * 256 + tid];
  __syncthreads();
  const float hev = he[g * 1024 + cq * 256 + tid];
  for (int n0 = 0; n0 < 64; n0 += 8) {
    float acc[8];
#pragma unroll
    for (int nn = 0; nn < 8; ++nn) acc[nn] = hev;
    for (int f = 0; f < 32; ++f) {
      float w = wgs[f][tid];
#pragma unroll
      for (int nn = 0; nn < 8; ++nn) acc[nn] += xns[n0 + nn][f] * w;
    }
#pragma unroll
    for (int nn = 0; nn < 8; ++nn)
      hbuf[(size_t)(g * 64 + n0 + nn) * 1024 + cq * 256 + tid] = __float2bfloat16(acc[nn]);
  }
}

// ---------------------------------------------------------------------------
// a_s[row,hd] = sum_e h[row, hd*256+e] * att_src[hd,e]; same for a_d.
// ---------------------------------------------------------------------------
__global__ __launch_bounds__(256) void as_ad_k(const bf16* __restrict__ hbuf,
                                               const float* __restrict__ att_s,
                                               const float* __restrict__ att_d,
                                               float* __restrict__ as_o,
                                               float* __restrict__ ad_o) {
  const int tid = threadIdx.x;
  const int lane = tid & 63, wv = tid >> 6;
  const int row = blockIdx.x * 4 + wv;
  const int hd = lane >> 4;
  const int e0 = (lane & 15) * 16;
  float as_r[16], ad_r[16];
#pragma unroll
  for (int q = 0; q < 4; ++q) {
    float4 v = *(const float4*)(att_s + hd * 256 + e0 + q * 4);
    as_r[q * 4 + 0] = v.x; as_r[q * 4 + 1] = v.y; as_r[q * 4 + 2] = v.z; as_r[q * 4 + 3] = v.w;
    float4 w = *(const float4*)(att_d + hd * 256 + e0 + q * 4);
    ad_r[q * 4 + 0] = w.x; ad_r[q * 4 + 1] = w.y; ad_r[q * 4 + 2] = w.z; ad_r[q * 4 + 3] = w.w;
  }
  const uint4* hp = (const uint4*)(hbuf + (size_t)row * 1024 + lane * 16);
  uint4 p0 = hp[0], p1 = hp[1];
  float hv[16];
  unp2(p0.x, hv[0], hv[1]);  unp2(p0.y, hv[2], hv[3]);
  unp2(p0.z, hv[4], hv[5]);  unp2(p0.w, hv[6], hv[7]);
  unp2(p1.x, hv[8], hv[9]);  unp2(p1.y, hv[10], hv[11]);
  unp2(p1.z, hv[12], hv[13]); unp2(p1.w, hv[14], hv[15]);
  float ps = 0.f, pd = 0.f;
#pragma unroll
  for (int i = 0; i < 16; ++i) { ps += as_r[i] * hv[i]; pd += ad_r[i] * hv[i]; }
#pragma unroll
  for (int m = 1; m < 16; m <<= 1) { ps += __shfl_xor(ps, m); pd += __shfl_xor(pd, m); }
  if ((lane & 15) == 0) { as_o[row * 4 + hd] = ps; ad_o[row * 4 + hd] = pd; }
}

// ---------------------------------------------------------------------------
// Per graph g: softmax over sources + head-mean aggregation + bias + relu.
// Writes seq as bf16 (same rounding point the GEMM applied before).
// ---------------------------------------------------------------------------
__global__ __launch_bounds__(256) void attn_agg_k(const bf16* __restrict__ hbuf,
                                                  const float* __restrict__ as_i,
                                                  const float* __restrict__ ad_i,
                                                  const float* __restrict__ bgat,
                                                  __bf16* __restrict__ seq) {
  __shared__ float ass[256], ads[256], bgs[256];
  __shared__ float alpha[4][64][64];   // [hd][j][i]
  __shared__ float hq[64][260];        // one head-quarter of h, fp32
  const int g = blockIdx.x, tid = threadIdx.x;
  ass[tid] = as_i[g * 256 + tid];
  ads[tid] = ad_i[g * 256 + tid];
  bgs[tid] = bgat[tid];
  __syncthreads();
  {
    const int hd = tid >> 6, i = tid & 63;
    const float ad = ads[i * 4 + hd];
    float m = -1e30f;
    for (int j = 0; j < 64; ++j) {
      float s = ad + ass[j * 4 + hd];
      s = s > 0.0f ? s : 0.2f * s;
      m = fmaxf(m, s);
    }
    float sum = 0.0f;
    for (int j = 0; j < 64; ++j) {
      float s = ad + ass[j * 4 + hd];
      s = s > 0.0f ? s : 0.2f * s;
      sum += __expf(s - m);
    }
    const float inv = 1.0f / sum;
    for (int j = 0; j < 64; ++j) {
      float s = ad + ass[j * 4 + hd];
      s = s > 0.0f ? s : 0.2f * s;
      alpha[hd][j][i] = __expf(s - m) * inv;
    }
  }
  const int i = tid & 63, eq = tid >> 6;
  float acc[64] = {};
  for (int hd = 0; hd < 4; ++hd) {
    __syncthreads();
    for (int idx = tid; idx < 2048; idx += 256) {
      int j = idx >> 5, ch = idx & 31;
      uint4 p = *(const uint4*)(hbuf + (size_t)(g * 64 + j) * 1024 + hd * 256 + ch * 8);
      float f0, f1, f2, f3, f4, f5, f6, f7;
      unp2(p.x, f0, f1); unp2(p.y, f2, f3); unp2(p.z, f4, f5); unp2(p.w, f6, f7);
      *(float4*)&hq[j][ch * 8] = make_float4(f0, f1, f2, f3);
      *(float4*)&hq[j][ch * 8 + 4] = make_float4(f4, f5, f6, f7);
    }
    __syncthreads();
    for (int j = 0; j < 64; ++j) {
      const float a = alpha[hd][j][i];
      const float* hr = &hq[j][eq * 64];
#pragma unroll
      for (int q = 0; q < 16; ++q) {
        float4 hv = *(const float4*)(hr + q * 4);
        acc[q * 4 + 0] += a * hv.x; acc[q * 4 + 1] += a * hv.y;
        acc[q * 4 + 2] += a * hv.z; acc[q * 4 + 3] += a * hv.w;
      }
    }
  }
  __bf16* op = seq + (size_t)g * 16384 + i * 256 + eq * 64;
#pragma unroll
  for (int q = 0; q < 8; ++q) {
    float4 lo, hi;
    lo.x = fmaxf(bgs[eq * 64 + q * 8 + 0] + 0.25f * acc[q * 8 + 0], 0.0f);
    lo.y = fmaxf(bgs[eq * 64 + q * 8 + 1] + 0.25f * acc[q * 8 + 1], 0.0f);
    lo.z = fmaxf(bgs[eq * 64 + q * 8 + 2] + 0.25f * acc[q * 8 + 2], 0.0f);
    lo.w = fmaxf(bgs[eq * 64 + q * 8 + 3] + 0.25f * acc[q * 8 + 3], 0.0f);
    hi.x = fmaxf(bgs[eq * 64 + q * 8 + 4] + 0.25f * acc[q * 8 + 4], 0.0f);
    hi.y = fmaxf(bgs[eq * 64 + q * 8 + 5] + 0.25f * acc[q * 8 + 5], 0.0f);
    hi.z = fmaxf(bgs[eq * 64 + q * 8 + 6] + 0.25f * acc[q * 8 + 6], 0.0f);
    hi.w = fmaxf(bgs[eq * 64 + q * 8 + 7] + 0.25f * acc[q * 8 + 7], 0.0f);
    *(bf16x8*)(op + q * 8) = cvt8(lo, hi);
  }
}

// ---------------------------------------------------------------------------
// out[b,o] = b_fc[o] + sum_k y1[b,31,k] * Wfc[k,o]
// ---------------------------------------------------------------------------
__global__ __launch_bounds__(256) void fc_k(const float* __restrict__ y1,
                                            const float* __restrict__ Wfc,
                                            const float* __restrict__ bfc,
                                            float* __restrict__ out) {
  __shared__ float As[8][1024];
  const int tid = threadIdx.x;
  for (int idx = tid; idx < 8192; idx += 256) {
    int b = idx >> 10, k = idx & 1023;
    As[b][k] = y1[(size_t)(b * 32 + 31) * 1024 + k];
  }
  __syncthreads();
  const int ol = tid >> 2, kq = tid & 3;
  const int o = blockIdx.x * 64 + ol;
  float acc[8] = {};
  if (o < 2016) {
    for (int i2 = 0; i2 < 256; ++i2) {
      int k = i2 * 4 + kq;
      float w = Wfc[(size_t)k * 2016 + o];
#pragma unroll
      for (int b = 0; b < 8; ++b) acc[b] += As[b][k] * w;
    }
  }
#pragma unroll
  for (int b = 0; b < 8; ++b) {
    acc[b] += __shfl_xor(acc[b], 1);
    acc[b] += __shfl_xor(acc[b], 2);
  }
  if (kq == 0 && o < 2016) {
#pragma unroll
    for (int b = 0; b < 8; ++b) out[b * 2016 + o] = acc[b] + bfc[o];
  }
}

// ---------------------------------------------------------------------------
extern "C" void kernel_launch(void* const* d_in, const int* in_sizes, int n_in,
                              void* d_out, int out_size, void* d_ws, size_t ws_size,
                              hipStream_t stream) {
  (void)in_sizes; (void)n_in; (void)out_size; (void)ws_size;
  const float* x_node = (const float*)d_in[0];
  const float* x_edge = (const float*)d_in[1];
  // d_in[2] = edge_index: complete graph + self loops -> dense; unused.
  const float* W_gat = (const float*)d_in[3];
  const float* att_s = (const float*)d_in[4];
  const float* att_d = (const float*)d_in[5];
  const float* b_gat = (const float*)d_in[6];
  const float* W_ih0 = (const float*)d_in[7];
  const float* W_hh0 = (const float*)d_in[8];
  const float* b_ih0 = (const float*)d_in[9];
  const float* b_hh0 = (const float*)d_in[10];
  const float* W_ih1 = (const float*)d_in[11];
  const float* W_hh1 = (const float*)d_in[12];
  const float* b_ih1 = (const float*)d_in[13];
  const float* b_hh1 = (const float*)d_in[14];
  const float* W_fc  = (const float*)d_in[15];
  const float* b_fc  = (const float*)d_in[16];

  char* ws = (char*)d_ws;
  size_t off = 0;
  float*  he  = (float*)(ws + off);  off += 256u * 1024 * 4;           // 1 MB
  float*  a_s = (float*)(ws + off);  off += 256u * 64 * 4 * 4;         // 256 KB
  float*  a_d = (float*)(ws + off);  off += 256u * 64 * 4 * 4;         // 256 KB
  bf16*   hb  = (bf16*)(ws + off);   off += 256u * 64 * 1024 * 2;      // 32 MB
  __bf16* seq = (__bf16*)(ws + off); off += 256u * 16384 * 2;          // 8 MB
  float*  X0  = (float*)(ws + off);  off += 256u * 3072 * 4;           // 3 MB
  float*  y0  = (float*)(ws + off);  off += 256u * 1024 * 4;           // 1 MB
  float*  X1  = (float*)(ws + off);  off += 256u * 3072 * 4;           // 3 MB
  float*  y1  = (float*)(ws + off);  off += 256u * 1024 * 4;           // 1 MB
  off = (off + 255) & ~(size_t)255;
  unsigned* bar = (unsigned*)(ws + off); off += 256;                   // barrier
  float*  Cp  = (float*)(ws + off);  off += (size_t)16 * 256 * 3072 * 4; // 48 MB

  // 1) he = x_edge @ W_gat[32:, :]   (M=256, N=1024, K=2016, B is [K,N]) SK=8
  mfma_gemm_k<false><<<dim3(8, 2, 8), 256, 0, stream>>>(
      x_edge, W_gat + 32 * 1024, Cp, 256, 1024, 2016, 2016, 1024, 8);
  reduce_k<<<256, 256, 0, stream>>>(Cp, nullptr, he, 256 * 1024, 1024, 8);
  // 2) h = node-proj + he (bf16)
  node_h_k<<<dim3(4, 256), 256, 0, stream>>>(x_node, W_gat, he, hb);
  // 3) attention logits
  as_ad_k<<<4096, 256, 0, stream>>>(hb, att_s, att_d, a_s, a_d);
  // 4) softmax + aggregation + relu -> seq [256, 16384] bf16
  attn_agg_k<<<256, 256, 0, stream>>>(hb, a_s, a_d, b_gat, seq);
  // 5) X0 = seq @ W_ih0^T + b_ih0   (M=256 full-tile, N=3072, K=16384) SK=16
  gemm_bt16_k<<<dim3(24, 1, 16), 256, 0, stream>>>(seq, W_ih0, Cp,
                                                   3072, 16384, 32);
  reduce_k<<<768, 256, 0, stream>>>(Cp, b_ih0, X0, 256 * 3072, 3072, 16);
  // 6) GRU layer 0: persistent scan (cheap grid barrier between steps)
  hipMemsetAsync(bar, 0, 8, stream);
  gru_persist_k<<<128, 256, 0, stream>>>(X0, W_hh0, b_hh0, y0, bar);
  // 7) X1 = y0 @ W_ih1^T + b_ih1    (M=256, N=3072, K=1024) SK=4
  mfma_gemm_k<true><<<dim3(24, 2, 4), 256, 0, stream>>>(
      y0, W_ih1, Cp, 256, 3072, 1024, 1024, 1024, 8);
  reduce_k<<<768, 256, 0, stream>>>(Cp, b_ih1, X1, 256 * 3072, 3072, 4);
  // 8) GRU layer 1: persistent scan
  hipMemsetAsync(bar, 0, 8, stream);
  gru_persist_k<<<128, 256, 0, stream>>>(X1, W_hh1, b_hh1, y1, bar);
  // 9) out = y1[:, 31] @ W_fc + b_fc
  fc_k<<<32, 256, 0, stream>>>(y1, W_fc, b_fc, (float*)d_out);
}

// Round 6
// 1231.809 us; speedup vs baseline: 2.8463x; 1.0496x over previous
//
#include <hip/hip_runtime.h>
#include <hip/hip_bf16.h>

using bf16 = __hip_bfloat16;
typedef __bf16 bf16x8 __attribute__((ext_vector_type(8)));
typedef float f32x4 __attribute__((ext_vector_type(4)));

// Sizes (fixed): B=8 S=32 N=64 F_NODE=32 TRI=2016 DIN=2048 H=4 DOUT=256 R=1024
// OUT=2016, G=B*S=256 graphs

__device__ __forceinline__ void unp2(unsigned int u, float& a, float& b) {
  a = __uint_as_float(u << 16);
  b = __uint_as_float(u & 0xffff0000u);
}

__device__ __forceinline__ bf16x8 cvt8(float4 a, float4 b) {
  bf16x8 r;
  r[0] = (__bf16)a.x; r[1] = (__bf16)a.y; r[2] = (__bf16)a.z; r[3] = (__bf16)a.w;
  r[4] = (__bf16)b.x; r[5] = (__bf16)b.y; r[6] = (__bf16)b.z; r[7] = (__bf16)b.w;
  return r;
}

__device__ __forceinline__ float ald(const float* p) {
  return __hip_atomic_load(p, __ATOMIC_RELAXED, __HIP_MEMORY_SCOPE_AGENT);
}
__device__ __forceinline__ void ast(float* p, float v) {
  __hip_atomic_store(p, v, __ATOMIC_RELAXED, __HIP_MEMORY_SCOPE_AGENT);
}

// ---------------------------------------------------------------------------
// Fence-free grid barrier.  All cross-block data moves via agent-scope
// (sc0 sc1) atomics that hit the coherence point directly, so NO cache-wide
// writeback/invalidate (__threadfence) is needed.  __syncthreads() drains
// vmcnt -> this block's coherent stores are globally visible on arrival.
// Monotonic epoch counter: no reset, no reset/arrive race.
// ---------------------------------------------------------------------------
__device__ __forceinline__ void grid_barrier(unsigned* cnt, unsigned* sns,
                                             unsigned nblk, unsigned epoch) {
  __syncthreads();
  if (threadIdx.x == 0) {
    unsigned old = __hip_atomic_fetch_add(cnt, 1u, __ATOMIC_RELAXED,
                                          __HIP_MEMORY_SCOPE_AGENT);
    if (old == nblk * epoch - 1u) {
      __hip_atomic_store(sns, epoch, __ATOMIC_RELAXED,
                         __HIP_MEMORY_SCOPE_AGENT);
    } else {
      while (__hip_atomic_load(sns, __ATOMIC_RELAXED,
                               __HIP_MEMORY_SCOPE_AGENT) < epoch)
        __builtin_amdgcn_s_sleep(1);
    }
  }
  __syncthreads();
}

// ---------------------------------------------------------------------------
// Persistent GRU layer scan.  128 blocks x 256 threads, 1 launch per layer.
// Block owns 8 hidden units j (j0=bid*8); wave w handles jA=j0+w, jB=j0+4+w.
// W_hh slice (24 x 1024 fp32 = 96 KB) LDS-resident for all 32 steps.
// h exchanged through agent-scope atomics (coherence point), no fences.
// ---------------------------------------------------------------------------
__global__ __launch_bounds__(256, 1) void gru_persist_k(
    const float* __restrict__ X,    // [256, 3072] gi
    const float* __restrict__ Whh,  // [3072, 1024]
    const float* __restrict__ bhh,  // [3072]
    float* __restrict__ y,          // [256, 1024]
    unsigned* __restrict__ bar) {
  __shared__ float ws[24][1024];    // [gate*8 + j_l][k]
  const int tid = threadIdx.x;
  const int w = tid >> 6, lane = tid & 63;
  const int b = lane >> 3, kg = lane & 7;
  const int j0 = blockIdx.x * 8;
  const int jA = j0 + w, jB = j0 + 4 + w;
#pragma unroll
  for (int q = 0; q < 24; ++q) {               // 6144 float4, 24/thread
    int idx = q * 256 + tid;
    int row = idx >> 8, k4 = (idx & 255) * 4;  // row = gate*8 + j_l
    int gr = (row >> 3) * 1024 + j0 + (row & 7);
    *(float4*)&ws[row][k4] = *(const float4*)&Whh[(size_t)gr * 1024 + k4];
  }
  const float brA = bhh[jA], bzA = bhh[1024 + jA], bnA = bhh[2048 + jA];
  const float brB = bhh[jB], bzB = bhh[1024 + jB], bnB = bhh[2048 + jB];
  __syncthreads();
  for (int s = 0; s < 32; ++s) {
    float4 hv[32];
    if (s == 0) {
#pragma unroll
      for (int m = 0; m < 32; ++m) hv[m] = make_float4(0.f, 0.f, 0.f, 0.f);
    } else {
      const float* hb_ = y + (size_t)(b * 32 + s - 1) * 1024;
#pragma unroll
      for (int m = 0; m < 32; ++m) {
        const int kf = 4 * (kg + 8 * m);
        hv[m].x = ald(hb_ + kf + 0);
        hv[m].y = ald(hb_ + kf + 1);
        hv[m].z = ald(hb_ + kf + 2);
        hv[m].w = ald(hb_ + kf + 3);
      }
    }
    float g0a = 0.f, g1a = 0.f, g2a = 0.f;
    float g0b = 0.f, g1b = 0.f, g2b = 0.f;
#pragma unroll
    for (int m = 0; m < 32; ++m) {
      const int kf = 4 * (kg + 8 * m);
      float4 h4 = hv[m];
      float4 wr_ = *(const float4*)&ws[w][kf];
      float4 wz_ = *(const float4*)&ws[8 + w][kf];
      float4 wn_ = *(const float4*)&ws[16 + w][kf];
      g0a += h4.x * wr_.x + h4.y * wr_.y + h4.z * wr_.z + h4.w * wr_.w;
      g1a += h4.x * wz_.x + h4.y * wz_.y + h4.z * wz_.z + h4.w * wz_.w;
      g2a += h4.x * wn_.x + h4.y * wn_.y + h4.z * wn_.z + h4.w * wn_.w;
      float4 vr_ = *(const float4*)&ws[4 + w][kf];
      float4 vz_ = *(const float4*)&ws[12 + w][kf];
      float4 vn_ = *(const float4*)&ws[20 + w][kf];
      g0b += h4.x * vr_.x + h4.y * vr_.y + h4.z * vr_.z + h4.w * vr_.w;
      g1b += h4.x * vz_.x + h4.y * vz_.y + h4.z * vz_.z + h4.w * vz_.w;
      g2b += h4.x * vn_.x + h4.y * vn_.y + h4.z * vn_.z + h4.w * vn_.w;
    }
#pragma unroll
    for (int d = 1; d < 8; d <<= 1) {
      g0a += __shfl_xor(g0a, d); g1a += __shfl_xor(g1a, d); g2a += __shfl_xor(g2a, d);
      g0b += __shfl_xor(g0b, d); g1b += __shfl_xor(g1b, d); g2b += __shfl_xor(g2b, d);
    }
    if (kg == 0) {
      const float* gip = X + (size_t)(b * 32 + s) * 3072;
      const float* hrow = y + (size_t)(b * 32 + s - 1) * 1024;
      float* yrow = y + (size_t)(b * 32 + s) * 1024;
      {
        float r = 1.0f / (1.0f + __expf(-(gip[jA] + g0a + brA)));
        float z = 1.0f / (1.0f + __expf(-(gip[1024 + jA] + g1a + bzA)));
        float n = tanhf(gip[2048 + jA] + r * (g2a + bnA));
        float hp = (s == 0) ? 0.f : ald(hrow + jA);
        ast(yrow + jA, (1.0f - z) * n + z * hp);
      }
      {
        float r = 1.0f / (1.0f + __expf(-(gip[jB] + g0b + brB)));
        float z = 1.0f / (1.0f + __expf(-(gip[1024 + jB] + g1b + bzB)));
        float n = tanhf(gip[2048 + jB] + r * (g2b + bnB));
        float hp = (s == 0) ? 0.f : ald(hrow + jB);
        ast(yrow + jB, (1.0f - z) * n + z * hp);
      }
    }
    if (s < 31) grid_barrier(bar, bar + 1, gridDim.x, (unsigned)(s + 1));
  }
}

// ---------------------------------------------------------------------------
// X0 GEMM: Cp[z][m][n] = sum_{k in chunk z} A[m,k]*B[n,k]
// A: [256, K] bf16 (full 32 bf16/row staged).  B: [N, K] fp32.
// M-tile = 256 (full M), N-tile 128, BK=32, register prefetch.
// ---------------------------------------------------------------------------
__global__ __launch_bounds__(256) void gemm_bt16_k(const __bf16* __restrict__ A,
                                                   const float* __restrict__ Bm,
                                                   float* __restrict__ Cp,
                                                   int N, int K, int ksper) {
  __shared__ __bf16 As[256][40];   // 80B row stride: aligned, ~2-way bank alias
  __shared__ __bf16 Bs[128][40];
  const int tid = threadIdx.x;
  const int bn = blockIdx.x * 128;
  const int lane = tid & 63, wv = tid >> 6;
  const int wr = wv >> 1, wc = wv & 1;
  const int lr = lane & 15, kh = lane >> 4;
  const int brow = tid >> 1, bhalf = tid & 1;
  f32x4 acc[8][4] = {};
  const int kstot = K >> 5;
  int ks0 = blockIdx.z * ksper;
  int ks1 = ks0 + ksper; if (ks1 > kstot) ks1 = kstot;
  uint4 ra0, ra1, ra2, ra3; float4 rb0, rb1, rb2, rb3;
  {
    const int k0 = ks0 << 5;
    const uint4* ap = (const uint4*)(A + (size_t)tid * K + k0);
    ra0 = ap[0]; ra1 = ap[1]; ra2 = ap[2]; ra3 = ap[3];
    const float* bp = Bm + (size_t)(bn + brow) * K + k0 + bhalf * 16;
    rb0 = ((const float4*)bp)[0]; rb1 = ((const float4*)bp)[1];
    rb2 = ((const float4*)bp)[2]; rb3 = ((const float4*)bp)[3];
  }
  for (int ks = ks0; ks < ks1; ++ks) {
    __syncthreads();
    *(uint4*)&As[tid][0]  = ra0;
    *(uint4*)&As[tid][8]  = ra1;
    *(uint4*)&As[tid][16] = ra2;
    *(uint4*)&As[tid][24] = ra3;
    *(bf16x8*)&Bs[brow][bhalf * 16] = cvt8(rb0, rb1);
    *(bf16x8*)&Bs[brow][bhalf * 16 + 8] = cvt8(rb2, rb3);
    __syncthreads();
    if (ks + 1 < ks1) {  // prefetch next K-tile into regs; overlaps with MFMA
      const int k0 = (ks + 1) << 5;
      const uint4* ap = (const uint4*)(A + (size_t)tid * K + k0);
      ra0 = ap[0]; ra1 = ap[1]; ra2 = ap[2]; ra3 = ap[3];
      const float* bp = Bm + (size_t)(bn + brow) * K + k0 + bhalf * 16;
      rb0 = ((const float4*)bp)[0]; rb1 = ((const float4*)bp)[1];
      rb2 = ((const float4*)bp)[2]; rb3 = ((const float4*)bp)[3];
    }
    bf16x8 bfv[4];
#pragma unroll
    for (int ni = 0; ni < 4; ++ni)
      bfv[ni] = *(const bf16x8*)&Bs[wc * 64 + ni * 16 + lr][kh * 8];
#pragma unroll
    for (int mi = 0; mi < 8; ++mi) {
      bf16x8 af = *(const bf16x8*)&As[wr * 128 + mi * 16 + lr][kh * 8];
#pragma unroll
      for (int ni = 0; ni < 4; ++ni)
        acc[mi][ni] = __builtin_amdgcn_mfma_f32_16x16x32_bf16(af, bfv[ni],
                                                              acc[mi][ni], 0, 0, 0);
    }
  }
  float* cp = Cp + (size_t)blockIdx.z * 256 * N;
#pragma unroll
  for (int mi = 0; mi < 8; ++mi) {
#pragma unroll
    for (int ni = 0; ni < 4; ++ni) {
      const int row = wr * 128 + mi * 16 + kh * 4;
      const int col = bn + wc * 64 + ni * 16 + lr;
#pragma unroll
      for (int j = 0; j < 4; ++j)
        cp[(size_t)(row + j) * N + col] = acc[mi][ni][j];
    }
  }
}

// ---------------------------------------------------------------------------
// fp32-input MFMA GEMM (he: B [K,N]; X1: B [N,K]) with split-K.
// ---------------------------------------------------------------------------
template <bool BT>
__global__ __launch_bounds__(256) void mfma_gemm_k(const float* __restrict__ A,
                                                   const float* __restrict__ Bm,
                                                   float* __restrict__ Cp,
                                                   int M, int N, int K,
                                                   int lda, int ldb, int ksper) {
  __shared__ __bf16 As[128][40];
  __shared__ __bf16 Bs[128][40];
  const int tid = threadIdx.x;
  const int bm = blockIdx.y * 128, bn = blockIdx.x * 128;
  const int lane = tid & 63, wv = tid >> 6;
  const int wr = wv >> 1, wc = wv & 1;
  const int lr = lane & 15, kh = lane >> 4;
  f32x4 acc[4][4] = {};
  const int kstot = K >> 5;
  int ks0 = blockIdx.z * ksper;
  int ks1 = ks0 + ksper; if (ks1 > kstot) ks1 = kstot;
  for (int ks = ks0; ks < ks1; ++ks) {
    const int k0 = ks << 5;
    __syncthreads();
    {
      const int row = tid >> 1, half = tid & 1;
      const float* ap = A + (size_t)(bm + row) * lda + k0 + half * 16;
      float4 f0 = ((const float4*)ap)[0], f1 = ((const float4*)ap)[1];
      float4 f2 = ((const float4*)ap)[2], f3 = ((const float4*)ap)[3];
      *(bf16x8*)&As[row][half * 16] = cvt8(f0, f1);
      *(bf16x8*)&As[row][half * 16 + 8] = cvt8(f2, f3);
    }
    if (BT) {
      const int row = tid >> 1, half = tid & 1;
      const float* bp = Bm + (size_t)(bn + row) * ldb + k0 + half * 16;
      float4 f0 = ((const float4*)bp)[0], f1 = ((const float4*)bp)[1];
      float4 f2 = ((const float4*)bp)[2], f3 = ((const float4*)bp)[3];
      *(bf16x8*)&Bs[row][half * 16] = cvt8(f0, f1);
      *(bf16x8*)&Bs[row][half * 16 + 8] = cvt8(f2, f3);
    } else {
      const int kk = tid >> 3, ng = tid & 7;
      const float* bp = Bm + (size_t)(k0 + kk) * ldb + bn + ng * 16;
      float4 f[4];
#pragma unroll
      for (int q = 0; q < 4; ++q) f[q] = ((const float4*)bp)[q];
#pragma unroll
      for (int q = 0; q < 4; ++q) {
        Bs[ng * 16 + q * 4 + 0][kk] = (__bf16)f[q].x;
        Bs[ng * 16 + q * 4 + 1][kk] = (__bf16)f[q].y;
        Bs[ng * 16 + q * 4 + 2][kk] = (__bf16)f[q].z;
        Bs[ng * 16 + q * 4 + 3][kk] = (__bf16)f[q].w;
      }
    }
    __syncthreads();
    bf16x8 af[4], bfv[4];
#pragma unroll
    for (int mi = 0; mi < 4; ++mi)
      af[mi] = *(const bf16x8*)&As[wr * 64 + mi * 16 + lr][kh * 8];
#pragma unroll
    for (int ni = 0; ni < 4; ++ni)
      bfv[ni] = *(const bf16x8*)&Bs[wc * 64 + ni * 16 + lr][kh * 8];
#pragma unroll
    for (int mi = 0; mi < 4; ++mi)
#pragma unroll
      for (int ni = 0; ni < 4; ++ni)
        acc[mi][ni] = __builtin_amdgcn_mfma_f32_16x16x32_bf16(af[mi], bfv[ni],
                                                              acc[mi][ni], 0, 0, 0);
  }
  float* cp = Cp + (size_t)blockIdx.z * M * N;
#pragma unroll
  for (int mi = 0; mi < 4; ++mi) {
#pragma unroll
    for (int ni = 0; ni < 4; ++ni) {
      const int row = bm + wr * 64 + mi * 16 + kh * 4;
      const int col = bn + wc * 64 + ni * 16 + lr;
#pragma unroll
      for (int j = 0; j < 4; ++j)
        cp[(size_t)(row + j) * N + col] = acc[mi][ni][j];
    }
  }
}

// C[i] = bias[i%N] + sum_sk Cp[sk][i]
__global__ __launch_bounds__(256) void reduce_k(const float* __restrict__ Cp,
                                                const float* __restrict__ bias,
                                                float* __restrict__ C,
                                                int MN, int N, int nsk) {
  int i = (blockIdx.x * 256 + threadIdx.x) * 4;
  if (i >= MN) return;
  float4 s = make_float4(0.f, 0.f, 0.f, 0.f);
  if (bias) s = *(const float4*)&bias[i % N];
  for (int sk = 0; sk < nsk; ++sk) {
    float4 p = *(const float4*)&Cp[(size_t)sk * MN + i];
    s.x += p.x; s.y += p.y; s.z += p.z; s.w += p.w;
  }
  *(float4*)&C[i] = s;
}

// ---------------------------------------------------------------------------
// h[g,n,c] = he[g,c] + sum_f x_node[g,n,f] * Wg[f,c]   -> stored bf16
// ---------------------------------------------------------------------------
__global__ __launch_bounds__(256) void node_h_k(const float* __restrict__ xn,
                                                const float* __restrict__ Wg,
                                                const float* __restrict__ he,
                                                bf16* __restrict__ hbuf) {
  __shared__ float xns[64][32];
  __shared__ float wgs[32][256];
  const int cq = blockIdx.x, g = blockIdx.y;
  const int tid = threadIdx.x;
  for (int idx = tid; idx < 2048; idx += 256) xns[idx >> 5][idx & 31] = xn[g * 2048 + idx];
  for (int r = 0; r < 32; ++r) wgs[r][tid] = Wg[r * 1024 + cq * 256 + tid];
  __syncthreads();
  const float hev = he[g * 1024 + cq * 256 + tid];
  for (int n0 = 0; n0 < 64; n0 += 8) {
    float acc[8];
#pragma unroll
    for (int nn = 0; nn < 8; ++nn) acc[nn] = hev;
    for (int f = 0; f < 32; ++f) {
      float w = wgs[f][tid];
#pragma unroll
      for (int nn = 0; nn < 8; ++nn) acc[nn] += xns[n0 + nn][f] * w;
    }
#pragma unroll
    for (int nn = 0; nn < 8; ++nn)
      hbuf[(size_t)(g * 64 + n0 + nn) * 1024 + cq * 256 + tid] = __float2bfloat16(acc[nn]);
  }
}

// ---------------------------------------------------------------------------
// a_s[row,hd] = sum_e h[row, hd*256+e] * att_src[hd,e]; same for a_d.
// ---------------------------------------------------------------------------
__global__ __launch_bounds__(256) void as_ad_k(const bf16* __restrict__ hbuf,
                                               const float* __restrict__ att_s,
                                               const float* __restrict__ att_d,
                                               float* __restrict__ as_o,
                                               float* __restrict__ ad_o) {
  const int tid = threadIdx.x;
  const int lane = tid & 63, wv = tid >> 6;
  const int row = blockIdx.x * 4 + wv;
  const int hd = lane >> 4;
  const int e0 = (lane & 15) * 16;
  float as_r[16], ad_r[16];
#pragma unroll
  for (int q = 0; q < 4; ++q) {
    float4 v = *(const float4*)(att_s + hd * 256 + e0 + q * 4);
    as_r[q * 4 + 0] = v.x; as_r[q * 4 + 1] = v.y; as_r[q * 4 + 2] = v.z; as_r[q * 4 + 3] = v.w;
    float4 w = *(const float4*)(att_d + hd * 256 + e0 + q * 4);
    ad_r[q * 4 + 0] = w.x; ad_r[q * 4 + 1] = w.y; ad_r[q * 4 + 2] = w.z; ad_r[q * 4 + 3] = w.w;
  }
  const uint4* hp = (const uint4*)(hbuf + (size_t)row * 1024 + lane * 16);
  uint4 p0 = hp[0], p1 = hp[1];
  float hv[16];
  unp2(p0.x, hv[0], hv[1]);  unp2(p0.y, hv[2], hv[3]);
  unp2(p0.z, hv[4], hv[5]);  unp2(p0.w, hv[6], hv[7]);
  unp2(p1.x, hv[8], hv[9]);  unp2(p1.y, hv[10], hv[11]);
  unp2(p1.z, hv[12], hv[13]); unp2(p1.w, hv[14], hv[15]);
  float ps = 0.f, pd = 0.f;
#pragma unroll
  for (int i = 0; i < 16; ++i) { ps += as_r[i] * hv[i]; pd += ad_r[i] * hv[i]; }
#pragma unroll
  for (int m = 1; m < 16; m <<= 1) { ps += __shfl_xor(ps, m); pd += __shfl_xor(pd, m); }
  if ((lane & 15) == 0) { as_o[row * 4 + hd] = ps; ad_o[row * 4 + hd] = pd; }
}

// ---------------------------------------------------------------------------
// Per graph g: softmax over sources + head-mean aggregation + bias + relu.
// Writes seq as bf16 (same rounding point the GEMM applied before).
// ---------------------------------------------------------------------------
__global__ __launch_bounds__(256) void attn_agg_k(const bf16* __restrict__ hbuf,
                                                  const float* __restrict__ as_i,
                                                  const float* __restrict__ ad_i,
                                                  const float* __restrict__ bgat,
                                                  __bf16* __restrict__ seq) {
  __shared__ float ass[256], ads[256], bgs[256];
  __shared__ float alpha[4][64][64];   // [hd][j][i]
  __shared__ float hq[64][260];        // one head-quarter of h, fp32
  const int g = blockIdx.x, tid = threadIdx.x;
  ass[tid] = as_i[g * 256 + tid];
  ads[tid] = ad_i[g * 256 + tid];
  bgs[tid] = bgat[tid];
  __syncthreads();
  {
    const int hd = tid >> 6, i = tid & 63;
    const float ad = ads[i * 4 + hd];
    float m = -1e30f;
    for (int j = 0; j < 64; ++j) {
      float s = ad + ass[j * 4 + hd];
      s = s > 0.0f ? s : 0.2f * s;
      m = fmaxf(m, s);
    }
    float sum = 0.0f;
    for (int j = 0; j < 64; ++j) {
      float s = ad + ass[j * 4 + hd];
      s = s > 0.0f ? s : 0.2f * s;
      sum += __expf(s - m);
    }
    const float inv = 1.0f / sum;
    for (int j = 0; j < 64; ++j) {
      float s = ad + ass[j * 4 + hd];
      s = s > 0.0f ? s : 0.2f * s;
      alpha[hd][j][i] = __expf(s - m) * inv;
    }
  }
  const int i = tid & 63, eq = tid >> 6;
  float acc[64] = {};
  for (int hd = 0; hd < 4; ++hd) {
    __syncthreads();
    for (int idx = tid; idx < 2048; idx += 256) {
      int j = idx >> 5, ch = idx & 31;
      uint4 p = *(const uint4*)(hbuf + (size_t)(g * 64 + j) * 1024 + hd * 256 + ch * 8);
      float f0, f1, f2, f3, f4, f5, f6, f7;
      unp2(p.x, f0, f1); unp2(p.y, f2, f3); unp2(p.z, f4, f5); unp2(p.w, f6, f7);
      *(float4*)&hq[j][ch * 8] = make_float4(f0, f1, f2, f3);
      *(float4*)&hq[j][ch * 8 + 4] = make_float4(f4, f5, f6, f7);
    }
    __syncthreads();
    for (int j = 0; j < 64; ++j) {
      const float a = alpha[hd][j][i];
      const float* hr = &hq[j][eq * 64];
#pragma unroll
      for (int q = 0; q < 16; ++q) {
        float4 hv = *(const float4*)(hr + q * 4);
        acc[q * 4 + 0] += a * hv.x; acc[q * 4 + 1] += a * hv.y;
        acc[q * 4 + 2] += a * hv.z; acc[q * 4 + 3] += a * hv.w;
      }
    }
  }
  __bf16* op = seq + (size_t)g * 16384 + i * 256 + eq * 64;
#pragma unroll
  for (int q = 0; q < 8; ++q) {
    float4 lo, hi;
    lo.x = fmaxf(bgs[eq * 64 + q * 8 + 0] + 0.25f * acc[q * 8 + 0], 0.0f);
    lo.y = fmaxf(bgs[eq * 64 + q * 8 + 1] + 0.25f * acc[q * 8 + 1], 0.0f);
    lo.z = fmaxf(bgs[eq * 64 + q * 8 + 2] + 0.25f * acc[q * 8 + 2], 0.0f);
    lo.w = fmaxf(bgs[eq * 64 + q * 8 + 3] + 0.25f * acc[q * 8 + 3], 0.0f);
    hi.x = fmaxf(bgs[eq * 64 + q * 8 + 4] + 0.25f * acc[q * 8 + 4], 0.0f);
    hi.y = fmaxf(bgs[eq * 64 + q * 8 + 5] + 0.25f * acc[q * 8 + 5], 0.0f);
    hi.z = fmaxf(bgs[eq * 64 + q * 8 + 6] + 0.25f * acc[q * 8 + 6], 0.0f);
    hi.w = fmaxf(bgs[eq * 64 + q * 8 + 7] + 0.25f * acc[q * 8 + 7], 0.0f);
    *(bf16x8*)(op + q * 8) = cvt8(lo, hi);
  }
}

// ---------------------------------------------------------------------------
// out[b,o] = b_fc[o] + sum_k y1[b,31,k] * Wfc[k,o]
// ---------------------------------------------------------------------------
__global__ __launch_bounds__(256) void fc_k(const float* __restrict__ y1,
                                            const float* __restrict__ Wfc,
                                            const float* __restrict__ bfc,
                                            float* __restrict__ out) {
  __shared__ float As[8][1024];
  const int tid = threadIdx.x;
  for (int idx = tid; idx < 8192; idx += 256) {
    int b = idx >> 10, k = idx & 1023;
    As[b][k] = y1[(size_t)(b * 32 + 31) * 1024 + k];
  }
  __syncthreads();
  const int ol = tid >> 2, kq = tid & 3;
  const int o = blockIdx.x * 64 + ol;
  float acc[8] = {};
  if (o < 2016) {
    for (int i2 = 0; i2 < 256; ++i2) {
      int k = i2 * 4 + kq;
      float w = Wfc[(size_t)k * 2016 + o];
#pragma unroll
      for (int b = 0; b < 8; ++b) acc[b] += As[b][k] * w;
    }
  }
#pragma unroll
  for (int b = 0; b < 8; ++b) {
    acc[b] += __shfl_xor(acc[b], 1);
    acc[b] += __shfl_xor(acc[b], 2);
  }
  if (kq == 0 && o < 2016) {
#pragma unroll
    for (int b = 0; b < 8; ++b) out[b * 2016 + o] = acc[b] + bfc[o];
  }
}

// ---------------------------------------------------------------------------
extern "C" void kernel_launch(void* const* d_in, const int* in_sizes, int n_in,
                              void* d_out, int out_size, void* d_ws, size_t ws_size,
                              hipStream_t stream) {
  (void)in_sizes; (void)n_in; (void)out_size; (void)ws_size;
  const float* x_node = (const float*)d_in[0];
  const float* x_edge = (const float*)d_in[1];
  // d_in[2] = edge_index: complete graph + self loops -> dense; unused.
  const float* W_gat = (const float*)d_in[3];
  const float* att_s = (const float*)d_in[4];
  const float* att_d = (const float*)d_in[5];
  const float* b_gat = (const float*)d_in[6];
  const float* W_ih0 = (const float*)d_in[7];
  const float* W_hh0 = (const float*)d_in[8];
  const float* b_ih0 = (const float*)d_in[9];
  const float* b_hh0 = (const float*)d_in[10];
  const float* W_ih1 = (const float*)d_in[11];
  const float* W_hh1 = (const float*)d_in[12];
  const float* b_ih1 = (const float*)d_in[13];
  const float* b_hh1 = (const float*)d_in[14];
  const float* W_fc  = (const float*)d_in[15];
  const float* b_fc  = (const float*)d_in[16];

  char* ws = (char*)d_ws;
  size_t off = 0;
  float*  he  = (float*)(ws + off);  off += 256u * 1024 * 4;           // 1 MB
  float*  a_s = (float*)(ws + off);  off += 256u * 64 * 4 * 4;         // 256 KB
  float*  a_d = (float*)(ws + off);  off += 256u * 64 * 4 * 4;         // 256 KB
  bf16*   hb  = (bf16*)(ws + off);   off += 256u * 64 * 1024 * 2;      // 32 MB
  __bf16* seq = (__bf16*)(ws + off); off += 256u * 16384 * 2;          // 8 MB
  float*  X0  = (float*)(ws + off);  off += 256u * 3072 * 4;           // 3 MB
  float*  y0  = (float*)(ws + off);  off += 256u * 1024 * 4;           // 1 MB
  float*  X1  = (float*)(ws + off);  off += 256u * 3072 * 4;           // 3 MB
  float*  y1  = (float*)(ws + off);  off += 256u * 1024 * 4;           // 1 MB
  off = (off + 255) & ~(size_t)255;
  unsigned* bar = (unsigned*)(ws + off); off += 256;                   // barrier
  float*  Cp  = (float*)(ws + off);  off += (size_t)16 * 256 * 3072 * 4; // 48 MB

  // 1) he = x_edge @ W_gat[32:, :]   (M=256, N=1024, K=2016, B is [K,N]) SK=8
  mfma_gemm_k<false><<<dim3(8, 2, 8), 256, 0, stream>>>(
      x_edge, W_gat + 32 * 1024, Cp, 256, 1024, 2016, 2016, 1024, 8);
  reduce_k<<<256, 256, 0, stream>>>(Cp, nullptr, he, 256 * 1024, 1024, 8);
  // 2) h = node-proj + he (bf16)
  node_h_k<<<dim3(4, 256), 256, 0, stream>>>(x_node, W_gat, he, hb);
  // 3) attention logits
  as_ad_k<<<4096, 256, 0, stream>>>(hb, att_s, att_d, a_s, a_d);
  // 4) softmax + aggregation + relu -> seq [256, 16384] bf16
  attn_agg_k<<<256, 256, 0, stream>>>(hb, a_s, a_d, b_gat, seq);
  // 5) X0 = seq @ W_ih0^T + b_ih0   (M=256 full-tile, N=3072, K=16384) SK=16
  gemm_bt16_k<<<dim3(24, 1, 16), 256, 0, stream>>>(seq, W_ih0, Cp,
                                                   3072, 16384, 32);
  reduce_k<<<768, 256, 0, stream>>>(Cp, b_ih0, X0, 256 * 3072, 3072, 16);
  // 6) GRU layer 0: persistent scan (fence-free barrier between steps)
  hipMemsetAsync(bar, 0, 8, stream);
  gru_persist_k<<<128, 256, 0, stream>>>(X0, W_hh0, b_hh0, y0, bar);
  // 7) X1 = y0 @ W_ih1^T + b_ih1    (M=256, N=3072, K=1024) SK=4
  mfma_gemm_k<true><<<dim3(24, 2, 4), 256, 0, stream>>>(
      y0, W_ih1, Cp, 256, 3072, 1024, 1024, 1024, 8);
  reduce_k<<<768, 256, 0, stream>>>(Cp, b_ih1, X1, 256 * 3072, 3072, 4);
  // 8) GRU layer 1: persistent scan
  hipMemsetAsync(bar, 0, 8, stream);
  gru_persist_k<<<128, 256, 0, stream>>>(X1, W_hh1, b_hh1, y1, bar);
  // 9) out = y1[:, 31] @ W_fc + b_fc
  fc_k<<<32, 256, 0, stream>>>(y1, W_fc, b_fc, (float*)d_out);
}

// Round 7
// 665.616 us; speedup vs baseline: 5.2675x; 1.8506x over previous
//
#include <hip/hip_runtime.h>
#include <hip/hip_bf16.h>

using bf16 = __hip_bfloat16;
typedef __bf16 bf16x8 __attribute__((ext_vector_type(8)));
typedef float f32x4 __attribute__((ext_vector_type(4)));

// Sizes (fixed): B=8 S=32 N=64 F_NODE=32 TRI=2016 DIN=2048 H=4 DOUT=256 R=1024
// OUT=2016, G=B*S=256 graphs

__device__ __forceinline__ void unp2(unsigned int u, float& a, float& b) {
  a = __uint_as_float(u << 16);
  b = __uint_as_float(u & 0xffff0000u);
}

__device__ __forceinline__ bf16x8 cvt8(float4 a, float4 b) {
  bf16x8 r;
  r[0] = (__bf16)a.x; r[1] = (__bf16)a.y; r[2] = (__bf16)a.z; r[3] = (__bf16)a.w;
  r[4] = (__bf16)b.x; r[5] = (__bf16)b.y; r[6] = (__bf16)b.z; r[7] = (__bf16)b.w;
  return r;
}

// ---------------------------------------------------------------------------
// One GRU step, lean version.  256 blocks x 256 threads; block owns 4 j's
// (one wave per j).  W_hh read directly from global (48 KB/block slice stays
// L2-resident across all 32 step launches: 32 blocks/XCD x 48 KB = 1.5 MB).
// h_prev staged to LDS with normal vectorized loads (kernel-boundary
// coherence).  Per lane: 384 FMA + 32 conflict-free ds_read_b128.
// ---------------------------------------------------------------------------
__global__ __launch_bounds__(256) void gru_step2_k(
    const float* __restrict__ X,    // [256, 3072] gi
    const float* __restrict__ Whh,  // [3072, 1024]
    const float* __restrict__ bhh,  // [3072]
    float* __restrict__ y,          // [256, 1024] rows; h state per (b,s)
    int s, int first) {
  __shared__ float hs[8][1024];     // 32 KB
  const int tid = threadIdx.x;
  if (first) {
#pragma unroll
    for (int q = 0; q < 8; ++q) {
      int idx = q * 256 + tid;
      *(float4*)&hs[idx >> 8][(idx & 255) * 4] = make_float4(0.f, 0.f, 0.f, 0.f);
    }
  } else {
#pragma unroll
    for (int q = 0; q < 8; ++q) {
      int idx = q * 256 + tid;
      int b = idx >> 8, kf = (idx & 255) * 4;
      *(float4*)&hs[b][kf] =
          *(const float4*)&y[(size_t)(b * 32 + s - 1) * 1024 + kf];
    }
  }
  __syncthreads();
  const int wv = tid >> 6, lane = tid & 63;
  const int j = blockIdx.x * 4 + wv;
  const float* Wr = Whh + (size_t)j * 1024;
  const float* Wz = Whh + (size_t)(1024 + j) * 1024;
  const float* Wn = Whh + (size_t)(2048 + j) * 1024;
  float accR[8] = {}, accZ[8] = {}, accN[8] = {};
#pragma unroll
  for (int kk = 0; kk < 4; ++kk) {
    const int k = kk * 256 + lane * 4;      // lanes contiguous 16B: coalesced
    float4 wr = *(const float4*)&Wr[k];
    float4 wz = *(const float4*)&Wz[k];
    float4 wn = *(const float4*)&Wn[k];
#pragma unroll
    for (int b = 0; b < 8; ++b) {
      float4 h4 = *(const float4*)&hs[b][k];  // conflict-free b128
      accR[b] += h4.x * wr.x + h4.y * wr.y + h4.z * wr.z + h4.w * wr.w;
      accZ[b] += h4.x * wz.x + h4.y * wz.y + h4.z * wz.z + h4.w * wz.w;
      accN[b] += h4.x * wn.x + h4.y * wn.y + h4.z * wn.z + h4.w * wn.w;
    }
  }
#pragma unroll
  for (int d = 1; d < 64; d <<= 1) {
#pragma unroll
    for (int b = 0; b < 8; ++b) {
      accR[b] += __shfl_xor(accR[b], d);
      accZ[b] += __shfl_xor(accZ[b], d);
      accN[b] += __shfl_xor(accN[b], d);
    }
  }
  if (lane < 8) {
    const int b = lane;
    float sr = 0.f, sz = 0.f, sn = 0.f;
#pragma unroll
    for (int bb = 0; bb < 8; ++bb)          // static-index select (no scratch)
      if (b == bb) { sr = accR[bb]; sz = accZ[bb]; sn = accN[bb]; }
    const float* gip = X + (size_t)(b * 32 + s) * 3072;
    float r = 1.0f / (1.0f + __expf(-(gip[j] + sr + bhh[j])));
    float z = 1.0f / (1.0f + __expf(-(gip[1024 + j] + sz + bhh[1024 + j])));
    float n = tanhf(gip[2048 + j] + r * (sn + bhh[2048 + j]));
    float hp = hs[b][j];
    y[(size_t)(b * 32 + s) * 1024 + j] = (1.0f - z) * n + z * hp;
  }
}

// ---------------------------------------------------------------------------
// X0 GEMM: Cp[z][m][n] = sum_{k in chunk z} A[m,k]*B[n,k]
// A: [256, K] bf16 (full 32 bf16/row staged).  B: [N, K] fp32.
// M-tile = 256 (full M), N-tile 128, BK=32, register prefetch.
// ---------------------------------------------------------------------------
__global__ __launch_bounds__(256) void gemm_bt16_k(const __bf16* __restrict__ A,
                                                   const float* __restrict__ Bm,
                                                   float* __restrict__ Cp,
                                                   int N, int K, int ksper) {
  __shared__ __bf16 As[256][40];   // 80B row stride: aligned, ~2-way bank alias
  __shared__ __bf16 Bs[128][40];
  const int tid = threadIdx.x;
  const int bn = blockIdx.x * 128;
  const int lane = tid & 63, wv = tid >> 6;
  const int wr = wv >> 1, wc = wv & 1;
  const int lr = lane & 15, kh = lane >> 4;
  const int brow = tid >> 1, bhalf = tid & 1;
  f32x4 acc[8][4] = {};
  const int kstot = K >> 5;
  int ks0 = blockIdx.z * ksper;
  int ks1 = ks0 + ksper; if (ks1 > kstot) ks1 = kstot;
  uint4 ra0, ra1, ra2, ra3; float4 rb0, rb1, rb2, rb3;
  {
    const int k0 = ks0 << 5;
    const uint4* ap = (const uint4*)(A + (size_t)tid * K + k0);
    ra0 = ap[0]; ra1 = ap[1]; ra2 = ap[2]; ra3 = ap[3];
    const float* bp = Bm + (size_t)(bn + brow) * K + k0 + bhalf * 16;
    rb0 = ((const float4*)bp)[0]; rb1 = ((const float4*)bp)[1];
    rb2 = ((const float4*)bp)[2]; rb3 = ((const float4*)bp)[3];
  }
  for (int ks = ks0; ks < ks1; ++ks) {
    __syncthreads();
    *(uint4*)&As[tid][0]  = ra0;
    *(uint4*)&As[tid][8]  = ra1;
    *(uint4*)&As[tid][16] = ra2;
    *(uint4*)&As[tid][24] = ra3;
    *(bf16x8*)&Bs[brow][bhalf * 16] = cvt8(rb0, rb1);
    *(bf16x8*)&Bs[brow][bhalf * 16 + 8] = cvt8(rb2, rb3);
    __syncthreads();
    if (ks + 1 < ks1) {  // prefetch next K-tile into regs; overlaps with MFMA
      const int k0 = (ks + 1) << 5;
      const uint4* ap = (const uint4*)(A + (size_t)tid * K + k0);
      ra0 = ap[0]; ra1 = ap[1]; ra2 = ap[2]; ra3 = ap[3];
      const float* bp = Bm + (size_t)(bn + brow) * K + k0 + bhalf * 16;
      rb0 = ((const float4*)bp)[0]; rb1 = ((const float4*)bp)[1];
      rb2 = ((const float4*)bp)[2]; rb3 = ((const float4*)bp)[3];
    }
    bf16x8 bfv[4];
#pragma unroll
    for (int ni = 0; ni < 4; ++ni)
      bfv[ni] = *(const bf16x8*)&Bs[wc * 64 + ni * 16 + lr][kh * 8];
#pragma unroll
    for (int mi = 0; mi < 8; ++mi) {
      bf16x8 af = *(const bf16x8*)&As[wr * 128 + mi * 16 + lr][kh * 8];
#pragma unroll
      for (int ni = 0; ni < 4; ++ni)
        acc[mi][ni] = __builtin_amdgcn_mfma_f32_16x16x32_bf16(af, bfv[ni],
                                                              acc[mi][ni], 0, 0, 0);
    }
  }
  float* cp = Cp + (size_t)blockIdx.z * 256 * N;
#pragma unroll
  for (int mi = 0; mi < 8; ++mi) {
#pragma unroll
    for (int ni = 0; ni < 4; ++ni) {
      const int row = wr * 128 + mi * 16 + kh * 4;
      const int col = bn + wc * 64 + ni * 16 + lr;
#pragma unroll
      for (int j = 0; j < 4; ++j)
        cp[(size_t)(row + j) * N + col] = acc[mi][ni][j];
    }
  }
}

// ---------------------------------------------------------------------------
// fp32-input MFMA GEMM (he: B [K,N]; X1: B [N,K]) with split-K.
// ---------------------------------------------------------------------------
template <bool BT>
__global__ __launch_bounds__(256) void mfma_gemm_k(const float* __restrict__ A,
                                                   const float* __restrict__ Bm,
                                                   float* __restrict__ Cp,
                                                   int M, int N, int K,
                                                   int lda, int ldb, int ksper) {
  __shared__ __bf16 As[128][40];
  __shared__ __bf16 Bs[128][40];
  const int tid = threadIdx.x;
  const int bm = blockIdx.y * 128, bn = blockIdx.x * 128;
  const int lane = tid & 63, wv = tid >> 6;
  const int wr = wv >> 1, wc = wv & 1;
  const int lr = lane & 15, kh = lane >> 4;
  f32x4 acc[4][4] = {};
  const int kstot = K >> 5;
  int ks0 = blockIdx.z * ksper;
  int ks1 = ks0 + ksper; if (ks1 > kstot) ks1 = kstot;
  for (int ks = ks0; ks < ks1; ++ks) {
    const int k0 = ks << 5;
    __syncthreads();
    {
      const int row = tid >> 1, half = tid & 1;
      const float* ap = A + (size_t)(bm + row) * lda + k0 + half * 16;
      float4 f0 = ((const float4*)ap)[0], f1 = ((const float4*)ap)[1];
      float4 f2 = ((const float4*)ap)[2], f3 = ((const float4*)ap)[3];
      *(bf16x8*)&As[row][half * 16] = cvt8(f0, f1);
      *(bf16x8*)&As[row][half * 16 + 8] = cvt8(f2, f3);
    }
    if (BT) {
      const int row = tid >> 1, half = tid & 1;
      const float* bp = Bm + (size_t)(bn + row) * ldb + k0 + half * 16;
      float4 f0 = ((const float4*)bp)[0], f1 = ((const float4*)bp)[1];
      float4 f2 = ((const float4*)bp)[2], f3 = ((const float4*)bp)[3];
      *(bf16x8*)&Bs[row][half * 16] = cvt8(f0, f1);
      *(bf16x8*)&Bs[row][half * 16 + 8] = cvt8(f2, f3);
    } else {
      const int kk = tid >> 3, ng = tid & 7;
      const float* bp = Bm + (size_t)(k0 + kk) * ldb + bn + ng * 16;
      float4 f[4];
#pragma unroll
      for (int q = 0; q < 4; ++q) f[q] = ((const float4*)bp)[q];
#pragma unroll
      for (int q = 0; q < 4; ++q) {
        Bs[ng * 16 + q * 4 + 0][kk] = (__bf16)f[q].x;
        Bs[ng * 16 + q * 4 + 1][kk] = (__bf16)f[q].y;
        Bs[ng * 16 + q * 4 + 2][kk] = (__bf16)f[q].z;
        Bs[ng * 16 + q * 4 + 3][kk] = (__bf16)f[q].w;
      }
    }
    __syncthreads();
    bf16x8 af[4], bfv[4];
#pragma unroll
    for (int mi = 0; mi < 4; ++mi)
      af[mi] = *(const bf16x8*)&As[wr * 64 + mi * 16 + lr][kh * 8];
#pragma unroll
    for (int ni = 0; ni < 4; ++ni)
      bfv[ni] = *(const bf16x8*)&Bs[wc * 64 + ni * 16 + lr][kh * 8];
#pragma unroll
    for (int mi = 0; mi < 4; ++mi)
#pragma unroll
      for (int ni = 0; ni < 4; ++ni)
        acc[mi][ni] = __builtin_amdgcn_mfma_f32_16x16x32_bf16(af[mi], bfv[ni],
                                                              acc[mi][ni], 0, 0, 0);
  }
  float* cp = Cp + (size_t)blockIdx.z * M * N;
#pragma unroll
  for (int mi = 0; mi < 4; ++mi) {
#pragma unroll
    for (int ni = 0; ni < 4; ++ni) {
      const int row = bm + wr * 64 + mi * 16 + kh * 4;
      const int col = bn + wc * 64 + ni * 16 + lr;
#pragma unroll
      for (int j = 0; j < 4; ++j)
        cp[(size_t)(row + j) * N + col] = acc[mi][ni][j];
    }
  }
}

// C[i] = bias[i%N] + sum_sk Cp[sk][i]
__global__ __launch_bounds__(256) void reduce_k(const float* __restrict__ Cp,
                                                const float* __restrict__ bias,
                                                float* __restrict__ C,
                                                int MN, int N, int nsk) {
  int i = (blockIdx.x * 256 + threadIdx.x) * 4;
  if (i >= MN) return;
  float4 s = make_float4(0.f, 0.f, 0.f, 0.f);
  if (bias) s = *(const float4*)&bias[i % N];
  for (int sk = 0; sk < nsk; ++sk) {
    float4 p = *(const float4*)&Cp[(size_t)sk * MN + i];
    s.x += p.x; s.y += p.y; s.z += p.z; s.w += p.w;
  }
  *(float4*)&C[i] = s;
}

// ---------------------------------------------------------------------------
// h[g,n,c] = he[g,c] + sum_f x_node[g,n,f] * Wg[f,c]   -> stored bf16
// ---------------------------------------------------------------------------
__global__ __launch_bounds__(256) void node_h_k(const float* __restrict__ xn,
                                                const float* __restrict__ Wg,
                                                const float* __restrict__ he,
                                                bf16* __restrict__ hbuf) {
  __shared__ float xns[64][32];
  __shared__ float wgs[32][256];
  const int cq = blockIdx.x, g = blockIdx.y;
  const int tid = threadIdx.x;
  for (int idx = tid; idx < 2048; idx += 256) xns[idx >> 5][idx & 31] = xn[g * 2048 + idx];
  for (int r = 0; r < 32; ++r) wgs[r][tid] = Wg[r * 1024 + cq * 256 + tid];
  __syncthreads();
  const float hev = he[g * 1024 + cq * 256 + tid];
  for (int n0 = 0; n0 < 64; n0 += 8) {
    float acc[8];
#pragma unroll
    for (int nn = 0; nn < 8; ++nn) acc[nn] = hev;
    for (int f = 0; f < 32; ++f) {
      float w = wgs[f][tid];
#pragma unroll
      for (int nn = 0; nn < 8; ++nn) acc[nn] += xns[n0 + nn][f] * w;
    }
#pragma unroll
    for (int nn = 0; nn < 8; ++nn)
      hbuf[(size_t)(g * 64 + n0 + nn) * 1024 + cq * 256 + tid] = __float2bfloat16(acc[nn]);
  }
}

// ---------------------------------------------------------------------------
// a_s[row,hd] = sum_e h[row, hd*256+e] * att_src[hd,e]; same for a_d.
// ---------------------------------------------------------------------------
__global__ __launch_bounds__(256) void as_ad_k(const bf16* __restrict__ hbuf,
                                               const float* __restrict__ att_s,
                                               const float* __restrict__ att_d,
                                               float* __restrict__ as_o,
                                               float* __restrict__ ad_o) {
  const int tid = threadIdx.x;
  const int lane = tid & 63, wv = tid >> 6;
  const int row = blockIdx.x * 4 + wv;
  const int hd = lane >> 4;
  const int e0 = (lane & 15) * 16;
  float as_r[16], ad_r[16];
#pragma unroll
  for (int q = 0; q < 4; ++q) {
    float4 v = *(const float4*)(att_s + hd * 256 + e0 + q * 4);
    as_r[q * 4 + 0] = v.x; as_r[q * 4 + 1] = v.y; as_r[q * 4 + 2] = v.z; as_r[q * 4 + 3] = v.w;
    float4 w = *(const float4*)(att_d + hd * 256 + e0 + q * 4);
    ad_r[q * 4 + 0] = w.x; ad_r[q * 4 + 1] = w.y; ad_r[q * 4 + 2] = w.z; ad_r[q * 4 + 3] = w.w;
  }
  const uint4* hp = (const uint4*)(hbuf + (size_t)row * 1024 + lane * 16);
  uint4 p0 = hp[0], p1 = hp[1];
  float hv[16];
  unp2(p0.x, hv[0], hv[1]);  unp2(p0.y, hv[2], hv[3]);
  unp2(p0.z, hv[4], hv[5]);  unp2(p0.w, hv[6], hv[7]);
  unp2(p1.x, hv[8], hv[9]);  unp2(p1.y, hv[10], hv[11]);
  unp2(p1.z, hv[12], hv[13]); unp2(p1.w, hv[14], hv[15]);
  float ps = 0.f, pd = 0.f;
#pragma unroll
  for (int i = 0; i < 16; ++i) { ps += as_r[i] * hv[i]; pd += ad_r[i] * hv[i]; }
#pragma unroll
  for (int m = 1; m < 16; m <<= 1) { ps += __shfl_xor(ps, m); pd += __shfl_xor(pd, m); }
  if ((lane & 15) == 0) { as_o[row * 4 + hd] = ps; ad_o[row * 4 + hd] = pd; }
}

// ---------------------------------------------------------------------------
// Per graph g: softmax over sources + head-mean aggregation + bias + relu.
// Writes seq as bf16 (same rounding point the GEMM applied before).
// ---------------------------------------------------------------------------
__global__ __launch_bounds__(256) void attn_agg_k(const bf16* __restrict__ hbuf,
                                                  const float* __restrict__ as_i,
                                                  const float* __restrict__ ad_i,
                                                  const float* __restrict__ bgat,
                                                  __bf16* __restrict__ seq) {
  __shared__ float ass[256], ads[256], bgs[256];
  __shared__ float alpha[4][64][64];   // [hd][j][i]
  __shared__ float hq[64][260];        // one head-quarter of h, fp32
  const int g = blockIdx.x, tid = threadIdx.x;
  ass[tid] = as_i[g * 256 + tid];
  ads[tid] = ad_i[g * 256 + tid];
  bgs[tid] = bgat[tid];
  __syncthreads();
  {
    const int hd = tid >> 6, i = tid & 63;
    const float ad = ads[i * 4 + hd];
    float m = -1e30f;
    for (int j = 0; j < 64; ++j) {
      float s = ad + ass[j * 4 + hd];
      s = s > 0.0f ? s : 0.2f * s;
      m = fmaxf(m, s);
    }
    float sum = 0.0f;
    for (int j = 0; j < 64; ++j) {
      float s = ad + ass[j * 4 + hd];
      s = s > 0.0f ? s : 0.2f * s;
      sum += __expf(s - m);
    }
    const float inv = 1.0f / sum;
    for (int j = 0; j < 64; ++j) {
      float s = ad + ass[j * 4 + hd];
      s = s > 0.0f ? s : 0.2f * s;
      alpha[hd][j][i] = __expf(s - m) * inv;
    }
  }
  const int i = tid & 63, eq = tid >> 6;
  float acc[64] = {};
  for (int hd = 0; hd < 4; ++hd) {
    __syncthreads();
    for (int idx = tid; idx < 2048; idx += 256) {
      int j = idx >> 5, ch = idx & 31;
      uint4 p = *(const uint4*)(hbuf + (size_t)(g * 64 + j) * 1024 + hd * 256 + ch * 8);
      float f0, f1, f2, f3, f4, f5, f6, f7;
      unp2(p.x, f0, f1); unp2(p.y, f2, f3); unp2(p.z, f4, f5); unp2(p.w, f6, f7);
      *(float4*)&hq[j][ch * 8] = make_float4(f0, f1, f2, f3);
      *(float4*)&hq[j][ch * 8 + 4] = make_float4(f4, f5, f6, f7);
    }
    __syncthreads();
    for (int j = 0; j < 64; ++j) {
      const float a = alpha[hd][j][i];
      const float* hr = &hq[j][eq * 64];
#pragma unroll
      for (int q = 0; q < 16; ++q) {
        float4 hv = *(const float4*)(hr + q * 4);
        acc[q * 4 + 0] += a * hv.x; acc[q * 4 + 1] += a * hv.y;
        acc[q * 4 + 2] += a * hv.z; acc[q * 4 + 3] += a * hv.w;
      }
    }
  }
  __bf16* op = seq + (size_t)g * 16384 + i * 256 + eq * 64;
#pragma unroll
  for (int q = 0; q < 8; ++q) {
    float4 lo, hi;
    lo.x = fmaxf(bgs[eq * 64 + q * 8 + 0] + 0.25f * acc[q * 8 + 0], 0.0f);
    lo.y = fmaxf(bgs[eq * 64 + q * 8 + 1] + 0.25f * acc[q * 8 + 1], 0.0f);
    lo.z = fmaxf(bgs[eq * 64 + q * 8 + 2] + 0.25f * acc[q * 8 + 2], 0.0f);
    lo.w = fmaxf(bgs[eq * 64 + q * 8 + 3] + 0.25f * acc[q * 8 + 3], 0.0f);
    hi.x = fmaxf(bgs[eq * 64 + q * 8 + 4] + 0.25f * acc[q * 8 + 4], 0.0f);
    hi.y = fmaxf(bgs[eq * 64 + q * 8 + 5] + 0.25f * acc[q * 8 + 5], 0.0f);
    hi.z = fmaxf(bgs[eq * 64 + q * 8 + 6] + 0.25f * acc[q * 8 + 6], 0.0f);
    hi.w = fmaxf(bgs[eq * 64 + q * 8 + 7] + 0.25f * acc[q * 8 + 7], 0.0f);
    *(bf16x8*)(op + q * 8) = cvt8(lo, hi);
  }
}

// ---------------------------------------------------------------------------
// out[b,o] = b_fc[o] + sum_k y1[b,31,k] * Wfc[k,o]
// ---------------------------------------------------------------------------
__global__ __launch_bounds__(256) void fc_k(const float* __restrict__ y1,
                                            const float* __restrict__ Wfc,
                                            const float* __restrict__ bfc,
                                            float* __restrict__ out) {
  __shared__ float As[8][1024];
  const int tid = threadIdx.x;
  for (int idx = tid; idx < 8192; idx += 256) {
    int b = idx >> 10, k = idx & 1023;
    As[b][k] = y1[(size_t)(b * 32 + 31) * 1024 + k];
  }
  __syncthreads();
  const int ol = tid >> 2, kq = tid & 3;
  const int o = blockIdx.x * 64 + ol;
  float acc[8] = {};
  if (o < 2016) {
    for (int i2 = 0; i2 < 256; ++i2) {
      int k = i2 * 4 + kq;
      float w = Wfc[(size_t)k * 2016 + o];
#pragma unroll
      for (int b = 0; b < 8; ++b) acc[b] += As[b][k] * w;
    }
  }
#pragma unroll
  for (int b = 0; b < 8; ++b) {
    acc[b] += __shfl_xor(acc[b], 1);
    acc[b] += __shfl_xor(acc[b], 2);
  }
  if (kq == 0 && o < 2016) {
#pragma unroll
    for (int b = 0; b < 8; ++b) out[b * 2016 + o] = acc[b] + bfc[o];
  }
}

// ---------------------------------------------------------------------------
extern "C" void kernel_launch(void* const* d_in, const int* in_sizes, int n_in,
                              void* d_out, int out_size, void* d_ws, size_t ws_size,
                              hipStream_t stream) {
  (void)in_sizes; (void)n_in; (void)out_size; (void)ws_size;
  const float* x_node = (const float*)d_in[0];
  const float* x_edge = (const float*)d_in[1];
  // d_in[2] = edge_index: complete graph + self loops -> dense; unused.
  const float* W_gat = (const float*)d_in[3];
  const float* att_s = (const float*)d_in[4];
  const float* att_d = (const float*)d_in[5];
  const float* b_gat = (const float*)d_in[6];
  const float* W_ih0 = (const float*)d_in[7];
  const float* W_hh0 = (const float*)d_in[8];
  const float* b_ih0 = (const float*)d_in[9];
  const float* b_hh0 = (const float*)d_in[10];
  const float* W_ih1 = (const float*)d_in[11];
  const float* W_hh1 = (const float*)d_in[12];
  const float* b_ih1 = (const float*)d_in[13];
  const float* b_hh1 = (const float*)d_in[14];
  const float* W_fc  = (const float*)d_in[15];
  const float* b_fc  = (const float*)d_in[16];

  char* ws = (char*)d_ws;
  size_t off = 0;
  float*  he  = (float*)(ws + off);  off += 256u * 1024 * 4;           // 1 MB
  float*  a_s = (float*)(ws + off);  off += 256u * 64 * 4 * 4;         // 256 KB
  float*  a_d = (float*)(ws + off);  off += 256u * 64 * 4 * 4;         // 256 KB
  bf16*   hb  = (bf16*)(ws + off);   off += 256u * 64 * 1024 * 2;      // 32 MB
  __bf16* seq = (__bf16*)(ws + off); off += 256u * 16384 * 2;          // 8 MB
  float*  X0  = (float*)(ws + off);  off += 256u * 3072 * 4;           // 3 MB
  float*  y0  = (float*)(ws + off);  off += 256u * 1024 * 4;           // 1 MB
  float*  X1  = (float*)(ws + off);  off += 256u * 3072 * 4;           // 3 MB
  float*  y1  = (float*)(ws + off);  off += 256u * 1024 * 4;           // 1 MB
  off = (off + 255) & ~(size_t)255;
  float*  Cp  = (float*)(ws + off);  off += (size_t)16 * 256 * 3072 * 4; // 48 MB

  // 1) he = x_edge @ W_gat[32:, :]   (M=256, N=1024, K=2016, B is [K,N]) SK=8
  mfma_gemm_k<false><<<dim3(8, 2, 8), 256, 0, stream>>>(
      x_edge, W_gat + 32 * 1024, Cp, 256, 1024, 2016, 2016, 1024, 8);
  reduce_k<<<256, 256, 0, stream>>>(Cp, nullptr, he, 256 * 1024, 1024, 8);
  // 2) h = node-proj + he (bf16)
  node_h_k<<<dim3(4, 256), 256, 0, stream>>>(x_node, W_gat, he, hb);
  // 3) attention logits
  as_ad_k<<<4096, 256, 0, stream>>>(hb, att_s, att_d, a_s, a_d);
  // 4) softmax + aggregation + relu -> seq [256, 16384] bf16
  attn_agg_k<<<256, 256, 0, stream>>>(hb, a_s, a_d, b_gat, seq);
  // 5) X0 = seq @ W_ih0^T + b_ih0   (M=256 full-tile, N=3072, K=16384) SK=16
  gemm_bt16_k<<<dim3(24, 1, 16), 256, 0, stream>>>(seq, W_ih0, Cp,
                                                   3072, 16384, 32);
  reduce_k<<<768, 256, 0, stream>>>(Cp, b_ih0, X0, 256 * 3072, 3072, 16);
  // 6) GRU layer 0: one lean launch per step (no grid barrier)
  for (int s = 0; s < 32; ++s)
    gru_step2_k<<<256, 256, 0, stream>>>(X0, W_hh0, b_hh0, y0, s, s == 0 ? 1 : 0);
  // 7) X1 = y0 @ W_ih1^T + b_ih1    (M=256, N=3072, K=1024) SK=4
  mfma_gemm_k<true><<<dim3(24, 2, 4), 256, 0, stream>>>(
      y0, W_ih1, Cp, 256, 3072, 1024, 1024, 1024, 8);
  reduce_k<<<768, 256, 0, stream>>>(Cp, b_ih1, X1, 256 * 3072, 3072, 4);
  // 8) GRU layer 1
  for (int s = 0; s < 32; ++s)
    gru_step2_k<<<256, 256, 0, stream>>>(X1, W_hh1, b_hh1, y1, s, s == 0 ? 1 : 0);
  // 9) out = y1[:, 31] @ W_fc + b_fc
  fc_k<<<32, 256, 0, stream>>>(y1, W_fc, b_fc, (float*)d_out);
}